// Round 5
// baseline (216.512 us; speedup 1.0000x reference)
//
#include <hip/hip_runtime.h>
#include <math.h>

#define GSZ 512
#define NSZ 256
#define NBATCH 8
#define MPTS 131072
#define PI_F 3.14159265358979f
#define BETA_F 13.8551004f
#define BETA2_F (BETA_F * BETA_F)
#define RSQ2 0.70710678f
// LDS pad: +1 float2 every 8 → strided radix-8 access conflict-reduced
#define PADIDX(i) ((i) + ((i) >> 3))

typedef float f32x4 __attribute__((ext_vector_type(4)));

// ---------------------------------------------------------------- helpers

// Exact asymptotic de-apodization: st ∈ [13.03, 13.855] so
// st/sinh(st) = 2·st·e^(−st)·(1+O(e^(−2st))), rel err < 5e-12.
__device__ __forceinline__ float apod(int i) {
    float x = (float)(i - 128);
    float arg = PI_F * 6.0f * x * (1.0f / 512.0f);
    float t = BETA2_F - arg * arg;
    float st = sqrtf(t);
    return 2.0f * st * __expf(-st);
}

// Branchless Kaiser-Bessel weight, large-x asymptotic i0 (3 transcendentals).
__device__ __forceinline__ float kbw(float u) {
    float t = 1.0f - u * u * (1.0f / 9.0f);
    float x = BETA_F * sqrtf(fmaxf(t, 0.0f));
    float xc = fmaxf(x, 0.35f);
    float R = __builtin_amdgcn_rsqf(xc);
    float R2 = R * R;
    float q = R * (0.39894228f + R2 * (0.04986779f + R2 * 0.02804702f));
    float w = __expf(xc) * q;
    return (t > 0.0f) ? w : 0.0f;
}

// DPP quad_perm cross-lane (no DS pipe)
template<int CTRL>
__device__ __forceinline__ float qdpp(float v) {
    int r = __builtin_amdgcn_mov_dpp(__float_as_int(v), CTRL, 0xF, 0xF, true);
    return __int_as_float(r);
}

__device__ __forceinline__ float2 cadd(float2 a, float2 b){ return make_float2(a.x+b.x, a.y+b.y); }
__device__ __forceinline__ float2 csub(float2 a, float2 b){ return make_float2(a.x-b.x, a.y-b.y); }
__device__ __forceinline__ float2 cmul(float2 a, float2 b){ return make_float2(a.x*b.x-a.y*b.y, a.x*b.y+a.y*b.x); }
__device__ __forceinline__ float2 mul_negi(float2 a){ return make_float2(a.y, -a.x); }
__device__ __forceinline__ float2 mul_posi(float2 a){ return make_float2(-a.y, a.x); }
__device__ __forceinline__ float2 mul_w81(float2 a){ return make_float2(RSQ2*(a.x+a.y), RSQ2*(a.y-a.x)); }
__device__ __forceinline__ float2 mul_w83(float2 a){ return make_float2(RSQ2*(a.y-a.x), -RSQ2*(a.x+a.y)); }

__device__ __forceinline__ void dft8_combine(float2 E0, float2 E1, float2 E2, float2 E3,
                                             float2 O0, float2 O1, float2 O2, float2 O3,
                                             float2* y) {
    float2 c1 = mul_w81(O1), c2 = mul_negi(O2), c3 = mul_w83(O3);
    y[0] = cadd(E0, O0); y[4] = csub(E0, O0);
    y[1] = cadd(E1, c1); y[5] = csub(E1, c1);
    y[2] = cadd(E2, c2); y[6] = csub(E2, c2);
    y[3] = cadd(E3, c3); y[7] = csub(E3, c3);
}

__device__ __forceinline__ void dft8(const float2* x, float2* y) {
    float2 a0=x[0], a1=x[2], a2=x[4], a3=x[6];
    float2 b0=x[1], b1=x[3], b2=x[5], b3=x[7];
    float2 ta0=cadd(a0,a2), ta1=csub(a0,a2), ta2=cadd(a1,a3), ta3=csub(a1,a3);
    float2 E0=cadd(ta0,ta2), E2=csub(ta0,ta2);
    float2 E1=cadd(ta1, mul_negi(ta3)), E3=cadd(ta1, mul_posi(ta3));
    float2 tb0=cadd(b0,b2), tb1=csub(b0,b2), tb2=cadd(b1,b3), tb3=csub(b1,b3);
    float2 O0=cadd(tb0,tb2), O2=csub(tb0,tb2);
    float2 O1=cadd(tb1, mul_negi(tb3)), O3=cadd(tb1, mul_posi(tb3));
    dft8_combine(E0,E1,E2,E3,O0,O1,O2,O3,y);
}

__device__ __forceinline__ void dft8_pruned(float2 x0, float2 x1, float2 x6, float2 x7, float2* y) {
    float2 E0 = cadd(x0, x6), E2 = csub(x0, x6);
    float2 E1 = cadd(x0, mul_posi(x6)), E3 = cadd(x0, mul_negi(x6));
    float2 O0 = cadd(x1, x7), O2 = csub(x1, x7);
    float2 O1 = cadd(x1, mul_posi(x7)), O3 = cadd(x1, mul_negi(x7));
    dft8_combine(E0,E1,E2,E3,O0,O1,O2,O3,y);
}

template<int S>
__device__ __forceinline__ void twiddle8(int t, float2* y) {
    if (S < 2) {
        int j = (S == 0) ? t : (t >> 3);
        const float scale = (S == 0) ? (-2.0f*PI_F/512.0f) : (-2.0f*PI_F/64.0f);
        float theta = scale * (float)j;
        float sn, cs;
        __sincosf(theta, &sn, &cs);              // sin FIRST, cos second
        float2 w = make_float2(cs, sn), wq = w;
        y[1] = cmul(y[1], wq);
        #pragma unroll
        for (int q = 2; q < 8; ++q) { wq = cmul(wq, w); y[q] = cmul(y[q], wq); }
    }
}

// ----- pair-cooperative half-butterfly primitives (pass 1, 128 thr/row) ---

__device__ __forceinline__ float2 pswap(float2 v) {
    return make_float2(qdpp<0xB1>(v.x), qdpp<0xB1>(v.y));
}

__device__ __forceinline__ void dft8_half(const float2* v, float2* EO) {
    float2 t0 = cadd(v[0], v[2]), t1 = csub(v[0], v[2]);
    float2 t2 = cadd(v[1], v[3]), t3 = csub(v[1], v[3]);
    EO[0] = cadd(t0, t2); EO[2] = csub(t0, t2);
    EO[1] = cadd(t1, mul_negi(t3)); EO[3] = cadd(t1, mul_posi(t3));
}

__device__ __forceinline__ void dft8p_half(float2 u0, float2 u1, float2* EO) {
    EO[0] = cadd(u0, u1); EO[2] = csub(u0, u1);
    EO[1] = cadd(u0, mul_posi(u1)); EO[3] = cadd(u0, mul_negi(u1));
}

__device__ __forceinline__ void combine_half(int h, const float2* V, float2* y) {
    float2 P0 = pswap(V[0]), P1 = pswap(V[1]), P2 = pswap(V[2]), P3 = pswap(V[3]);
    float2 E0 = h ? P0 : V[0], O0 = h ? V[0] : P0;
    float2 E1 = h ? P1 : V[1], O1 = h ? V[1] : P1;
    float2 E2 = h ? P2 : V[2], O2 = h ? V[2] : P2;
    float2 E3 = h ? P3 : V[3], O3 = h ? V[3] : P3;
    float2 c1 = mul_w81(O1), c2 = mul_negi(O2), c3 = mul_w83(O3);
    float s = h ? -1.0f : 1.0f;
    y[0] = make_float2(fmaf(s, O0.x, E0.x), fmaf(s, O0.y, E0.y));
    y[1] = make_float2(fmaf(s, c1.x, E1.x), fmaf(s, c1.y, E1.y));
    y[2] = make_float2(fmaf(s, c2.x, E2.x), fmaf(s, c2.y, E2.y));
    y[3] = make_float2(fmaf(s, c3.x, E3.x), fmaf(s, c3.y, E3.y));
}

__device__ __forceinline__ void twiddle4h(int jidx, float scale, int h, float2* y) {
    float theta = scale * (float)jidx;
    float sn, cs;
    __sincosf(theta, &sn, &cs);                  // sin FIRST, cos second
    float2 w = make_float2(cs, sn);
    float2 w2 = cmul(w, w);
    float2 w4 = cmul(w2, w2);
    float2 m = h ? w4 : make_float2(1.0f, 0.0f);
    y[0] = cmul(y[0], m);
    float2 wq = cmul(m, w); y[1] = cmul(y[1], wq);
    wq = cmul(wq, w);       y[2] = cmul(y[2], wq);
    wq = cmul(wq, w);       y[3] = cmul(y[3], wq);
}

// ---------------------------------------------------------------- pass 1
// Pair-cooperative row FFT (r4, verified) + cursor zeroing (block 0).
// cursors consumed only by the NEXT kernel (scatter) — stream-ordered.
__global__ __launch_bounds__(256) void pass1_rowfft(const float* __restrict__ image,
                                                    float2* __restrict__ T,
                                                    int* __restrict__ cursors) {
    __shared__ float2 sm[2][2][578];
    int tid = threadIdx.x;
    if (blockIdx.x == 0) {
        for (int z = tid; z < 1024; z += 256) cursors[z] = 0;
    }
    int r = tid >> 7;                               // row within block {0,1}
    int tt = tid & 127;
    int h = tt & 1;                                 // butterfly half (E/O)
    int b = tt >> 1;                                // butterfly index 0..63
    int blk = blockIdx.x;
    int p = blk & 3;                                // batch pair 0..3
    int g = blk >> 2;                               // 0..127
    int rp = (g << 1) + r;                          // compact row 0..255
    int y = (rp < 128) ? rp : (rp + 256);
    int iy = (y < 128) ? (y + 128) : (y - 384);
    float ay = apod(iy);
    const float* irow0 = image + ((size_t)((2 * p)     * NSZ + iy)) * NSZ;
    const float* irow1 = image + ((size_t)((2 * p + 1) * NSZ + iy)) * NSZ;

    float2 y4[4];
    {
        int iA = h ? (b + 192) : (b + 128);
        int iB = h ? (b + 64)  : b;
        float wA = ay * apod(iA), wB = ay * apod(iB);
        float2 u0 = make_float2(irow0[iA] * wA, irow1[iA] * wA);
        float2 u1 = make_float2(irow0[iB] * wB, irow1[iB] * wB);
        float2 EO[4];
        dft8p_half(u0, u1, EO);
        combine_half(h, EO, y4);
        twiddle4h(b, -2.0f * PI_F / 512.0f, h, y4);
    }
    float2* A  = sm[0][r];
    float2* Bf = sm[1][r];
    #pragma unroll
    for (int qq = 0; qq < 4; ++qq) A[PADIDX((b << 3) + (h << 2) + qq)] = y4[qq];
    __syncthreads();
    {
        float2 v[4];
        #pragma unroll
        for (int i = 0; i < 4; ++i) v[i] = A[PADIDX(b + (((i << 1) + h) << 6))];
        float2 EO[4];
        dft8_half(v, EO);
        combine_half(h, EO, y4);
        twiddle4h(b >> 3, -2.0f * PI_F / 64.0f, h, y4);
        int base = (b & 7) + ((b >> 3) << 6);
        #pragma unroll
        for (int qq = 0; qq < 4; ++qq) Bf[PADIDX(base + (((h << 2) + qq) << 3))] = y4[qq];
    }
    __syncthreads();
    {
        float2 v[4];
        #pragma unroll
        for (int i = 0; i < 4; ++i) v[i] = Bf[PADIDX(b + (((i << 1) + h) << 6))];
        float2 EO[4];
        dft8_half(v, EO);
        combine_half(h, EO, y4);
        float2* Trow = T + (((size_t)(p << 8) + rp) << 9);
        #pragma unroll
        for (int qq = 0; qq < 4; ++qq) Trow[b + (((h << 2) + qq) << 6)] = y4[qq];
    }
}

// ---------------------------------------------------------------- pass 2
// blocks [0,256): batch-pair packed column FFT + Hermitian unpack (verified).
// blocks [256,512): point scatter — band-sort {tm1,tm2,dcf,m} into fixed
// 2048-slot slices per (batch, 4-row band) via atomic cursors (zeroed by
// pass1; no prefix scan needed, capacity margin ≈ 32σ).
__global__ __launch_bounds__(256) void pass2_colfft(const float2* __restrict__ T,
                                                    float2* __restrict__ kgrid,
                                                    const float* __restrict__ ktraj,
                                                    const float* __restrict__ dcf,
                                                    int* __restrict__ cursors,
                                                    float4* __restrict__ sortedpt) {
    __shared__ float2 B[8][578];
    int tid = threadIdx.x;
    int blk = blockIdx.x;

    if (blk >= 256) {
        // ---------------- scatter pass
        int u = blk - 256;
        int bs = u >> 5, seg = u & 31;            // 8 batches × 32 segs × 4096 pts
        const float SCALE = (float)GSZ / (2.0f * PI_F);
        const float* kt1 = ktraj + (size_t)(bs * 2) * MPTS;
        const float* kt2 = kt1 + MPTS;
        const float* dcfb = dcf + ((size_t)bs << 17);
        int* cur = cursors + (bs << 7);
        float4* sp = sortedpt + ((size_t)bs << 18);   // 128 bands * 2048 slots
        #pragma unroll 4
        for (int k = 0; k < 16; ++k) {
            int m = (seg << 12) + (k << 8) + tid;
            float t1 = kt1[m] * SCALE;
            float t2 = kt2[m] * SCALE;
            float d  = dcfb[m];
            int key = (((int)floorf(t1)) & 511) >> 2;     // 4-row band
            int pos = atomicAdd(cur + key, 1);
            if (pos < 2048)
                sp[((size_t)key << 11) + pos] = make_float4(t1, t2, d, __int_as_float(m));
        }
        return;
    }

    int p = blk & 3;                                // batch pair
    int g = blk >> 2;                               // 0..63 col group
    const float2* Tb = T + ((size_t)p << 17);       // 256*512 per pair
    float2* Kb0 = kgrid + ((size_t)(2 * p) << 18);
    float2* Kb1 = Kb0 + ((size_t)1 << 18);

    #define COLG(c) ((g > 0) ? (((c) < 4) ? ((g << 2) + (c)) : (505 - (g << 2) + (c))) \
                             : (((c) < 4) ? (c) : (((c) == 7) ? 256 : (505 + (c)))))

    {
        int c = tid & 7, r0 = tid >> 3;             // r0 0..31
        int colg = COLG(c);
        #pragma unroll
        for (int k = 0; k < 8; ++k) {
            int rr = r0 + (k << 5);
            B[c][PADIDX(rr)] = Tb[((size_t)rr << 9) + colg];
        }
    }
    __syncthreads();
    int t = tid & 63;
    int c0 = tid >> 6;                              // slots c0 and c0+4
    float2* Ba = B[c0];
    float2* Bb = B[c0 + 4];
    float2 ya[8], yb[8];
    {
        float2 a0 = Ba[PADIDX(t)],       a1 = Ba[PADIDX(t + 64)];
        float2 a6 = Ba[PADIDX(t + 128)], a7 = Ba[PADIDX(t + 192)];
        float2 b0 = Bb[PADIDX(t)],       b1 = Bb[PADIDX(t + 64)];
        float2 b6 = Bb[PADIDX(t + 128)], b7 = Bb[PADIDX(t + 192)];
        dft8_pruned(a0, a1, a6, a7, ya); twiddle8<0>(t, ya);
        dft8_pruned(b0, b1, b6, b7, yb); twiddle8<0>(t, yb);
    }
    __syncthreads();
    #pragma unroll
    for (int q = 0; q < 8; ++q) {
        Ba[PADIDX((t << 3) + q)] = ya[q];
        Bb[PADIDX((t << 3) + q)] = yb[q];
    }
    __syncthreads();
    {
        float2 xa[8], xb[8];
        #pragma unroll
        for (int pp = 0; pp < 8; ++pp) { xa[pp] = Ba[PADIDX(t + (pp << 6))]; xb[pp] = Bb[PADIDX(t + (pp << 6))]; }
        dft8(xa, ya); twiddle8<1>(t, ya);
        dft8(xb, yb); twiddle8<1>(t, yb);
    }
    __syncthreads();
    {
        int j = t >> 3, k = t & 7, base = k + (j << 6);
        #pragma unroll
        for (int q = 0; q < 8; ++q) {
            Ba[PADIDX(base + (q << 3))] = ya[q];
            Bb[PADIDX(base + (q << 3))] = yb[q];
        }
    }
    __syncthreads();
    {
        float2 xa[8], xb[8];
        #pragma unroll
        for (int pp = 0; pp < 8; ++pp) { xa[pp] = Ba[PADIDX(t + (pp << 6))]; xb[pp] = Bb[PADIDX(t + (pp << 6))]; }
        dft8(xa, ya);
        dft8(xb, yb);
    }
    __syncthreads();
    #pragma unroll
    for (int q = 0; q < 8; ++q) {
        Ba[PADIDX(t + (q << 6))] = ya[q];
        Bb[PADIDX(t + (q << 6))] = yb[q];
    }
    __syncthreads();
    {
        int c = tid & 7, r0 = tid >> 3;
        int colg = COLG(c);
        int mc = 7 - c;
        if (g == 0) { if (c == 0) mc = 0; else if (c == 7) mc = 7; }
        #pragma unroll
        for (int k = 0; k < 16; ++k) {
            int rr = r0 + (k << 5);
            int mr = (512 - rr) & 511;
            float2 Z = B[c][PADIDX(rr)];
            float2 M = B[mc][PADIDX(mr)];
            float2 K0 = make_float2(0.5f * (Z.x + M.x), 0.5f * (Z.y - M.y));
            float2 K1 = make_float2(0.5f * (Z.y + M.y), 0.5f * (M.x - Z.x));
            size_t off = ((size_t)rr << 9) + colg;
            Kb0[off] = K0;
            Kb1[off] = K1;
        }
    }
    #undef COLG
}

// ---------------------------------------------------------------- pass 3
// Band-local KB gather: block = (batch, 4-row band). Stage the band's
// 9 rows (4 + 5 halo, wrap-masked) into LDS (row stride 1028 floats,
// 16B-aligned), then per point: ONE coalesced float4 load (sorted stream)
// + 6 ds_read_b128 + the verified weight/FMA/DPP math + guarded scatter
// store of out[m]. VMEM requests drop ~27/pt → ~3/pt.
__global__ __launch_bounds__(256) void interp_kb(const float2* __restrict__ kgrid,
                                                 const int* __restrict__ cursors,
                                                 const float4* __restrict__ sortedpt,
                                                 float* __restrict__ out) {
    __shared__ float lds[9 * 1028];                 // 37,008 B → 4 blocks/CU
    int tid = threadIdx.x;
    int blk = blockIdx.x;
    int b = blk & 7;                                // XCD affinity on batch
    int band = blk >> 3;                            // 0..127
    int j = tid & 3;                                // lane within quad
    int q = tid >> 2;                               // quad 0..63
    int j2 = j << 1;
    float fjm2 = (float)(j - 2), fjp2 = (float)(j + 2);

    int cnt = cursors[(b << 7) + band];
    cnt = (cnt > 2048) ? 2048 : cnt;
    if (cnt == 0) return;                           // block-uniform, pre-sync

    // ---- stage 9 rows of kgrid[b] (global rows band*4-2 .. +6, mod 512)
    const float2* Kb = kgrid + ((size_t)b << 18);
    #pragma unroll
    for (int r = 0; r < 9; ++r) {
        int gr = ((band << 2) - 2 + r) & 511;
        const float4* src = (const float4*)(Kb + ((size_t)gr << 9));
        *(float4*)(lds + r * 1028 + (tid << 2)) = src[tid];
    }
    __syncthreads();

    const float4* sp = sortedpt + ((size_t)b << 18) + ((size_t)band << 11);
    float* out_re = out + ((size_t)b << 17);
    float* out_im = out_re + (size_t)NBATCH * MPTS;

    int iters = (cnt + 63) >> 6;
    for (int it = 0; it < iters; ++it) {
        int pidx = (it << 6) + q;
        bool valid = pidx < cnt;
        float4 pt = sp[valid ? pidx : 0];           // quad-uniform address
        float tm1 = pt.x, tm2 = pt.y, dd = pt.z;
        int m = __float_as_int(pt.w);

        float f1 = floorf(tm1), f2 = floorf(tm2);
        int if1 = (int)f1, if2 = (int)f2;
        int e0 = (if2 - 2) & ~1;                    // even base col
        int cpair = (e0 + j2) & 511;                // even → pair in-row
        int lr = (if1 & 511) - (band << 2);         // 0..3 (band-local row)

        // ---- weights (identical math to verified kernel)
        float u2 = tm2 - (float)(e0 + j2);
        float w2a = kbw(u2);
        float w2b = kbw(u2 - 1.0f);
        float fr1 = tm1 - f1;
        float w1A = kbw(fr1 - fjm2);
        float w1B = kbw(fr1 - fjp2);
        float w0_ = qdpp<0x00>(w1A);
        float w1_ = qdpp<0x55>(w1A);
        float w2_ = qdpp<0xAA>(w1A);
        float w3_ = qdpp<0xFF>(w1A);
        float w4_ = qdpp<0x00>(w1B);
        float w5_ = qdpp<0x55>(w1B);

        // ---- 6 row reads from LDS (16B aligned: cpair even, stride 4112B)
        const float* lp = lds + (cpair << 1);
        f32x4 v0 = *(const f32x4*)(lp + (lr + 0) * 1028);
        f32x4 v1 = *(const f32x4*)(lp + (lr + 1) * 1028);
        f32x4 v2 = *(const f32x4*)(lp + (lr + 2) * 1028);
        f32x4 v3 = *(const f32x4*)(lp + (lr + 3) * 1028);
        f32x4 v4 = *(const f32x4*)(lp + (lr + 4) * 1028);
        f32x4 v5 = *(const f32x4*)(lp + (lr + 5) * 1028);

        // ---- fma chain (bit-identical ordering to verified kernel)
        float c0re = w0_ * v0.x, c0im = w0_ * v0.y;
        float c1re = w0_ * v0.z, c1im = w0_ * v0.w;
        c0re = fmaf(w1_, v1.x, c0re); c0im = fmaf(w1_, v1.y, c0im);
        c1re = fmaf(w1_, v1.z, c1re); c1im = fmaf(w1_, v1.w, c1im);
        c0re = fmaf(w2_, v2.x, c0re); c0im = fmaf(w2_, v2.y, c0im);
        c1re = fmaf(w2_, v2.z, c1re); c1im = fmaf(w2_, v2.w, c1im);
        c0re = fmaf(w3_, v3.x, c0re); c0im = fmaf(w3_, v3.y, c0im);
        c1re = fmaf(w3_, v3.z, c1re); c1im = fmaf(w3_, v3.w, c1im);
        c0re = fmaf(w4_, v4.x, c0re); c0im = fmaf(w4_, v4.y, c0im);
        c1re = fmaf(w4_, v4.z, c1re); c1im = fmaf(w4_, v4.w, c1im);
        c0re = fmaf(w5_, v5.x, c0re); c0im = fmaf(w5_, v5.y, c0im);
        c1re = fmaf(w5_, v5.z, c1re); c1im = fmaf(w5_, v5.w, c1im);
        float p_re = fmaf(w2a, c0re, w2b * c1re);
        float p_im = fmaf(w2a, c0im, w2b * c1im);
        p_re += qdpp<0xB1>(p_re); p_re += qdpp<0x4E>(p_re);
        p_im += qdpp<0xB1>(p_im); p_im += qdpp<0x4E>(p_im);

        if (valid) {
            if (j == 0) out_re[m] = p_re * dd;
            else if (j == 1) out_im[m] = p_im * dd;
        }
    }
}

// ---------------------------------------------------------------- launch

extern "C" void kernel_launch(void* const* d_in, const int* in_sizes, int n_in,
                              void* d_out, int out_size, void* d_ws, size_t ws_size,
                              hipStream_t stream) {
    const float* image = (const float*)d_in[0];   // (8,256,256) f32
    const float* ktraj = (const float*)d_in[1];   // (8,2,131072) f32
    const float* dcf   = (const float*)d_in[2];   // (8,131072) f32
    float* out = (float*)d_out;                   // (2,8,131072) f32

    // workspace layout (bytes):
    //   T        @ 0          4,194,304   (4 pairs * 256*512 c64)
    //   kgrid    @ 4,194,304  16,777,216  (8 * 512*512 c64)
    //   cursors  @ 20,971,520 4,096       (8 * 128 int)
    //   sortedpt @ 20,975,616 33,554,432  (8 * 128 bands * 2048 * float4)
    float2* T        = (float2*)d_ws;
    float2* kgrid    = T + (size_t)4 * 256 * GSZ;
    int*    cursors  = (int*)((char*)d_ws + 20971520);
    float4* sortedpt = (float4*)((char*)d_ws + 20975616);

    pass1_rowfft<<<512, 256, 0, stream>>>(image, T, cursors);
    pass2_colfft<<<512, 256, 0, stream>>>(T, kgrid, ktraj, dcf, cursors, sortedpt);
    interp_kb<<<1024, 256, 0, stream>>>(kgrid, cursors, sortedpt, out);
}

// Round 6
// 123.285 us; speedup vs baseline: 1.7562x; 1.7562x over previous
//
#include <hip/hip_runtime.h>
#include <math.h>

#define GSZ 512
#define NSZ 256
#define NBATCH 8
#define MPTS 131072
#define PI_F 3.14159265358979f
#define BETA_F 13.8551004f
#define BETA2_F (BETA_F * BETA_F)
#define RSQ2 0.70710678f
// LDS pad: +1 float2 every 8 → strided radix-8 access conflict-reduced
#define PADIDX(i) ((i) + ((i) >> 3))

typedef float f32x4 __attribute__((ext_vector_type(4)));

// ---------------------------------------------------------------- helpers

// Exact asymptotic de-apodization: st ∈ [13.03, 13.855] so
// st/sinh(st) = 2·st·e^(−st)·(1+O(e^(−2st))), rel err < 5e-12.
__device__ __forceinline__ float apod(int i) {
    float x = (float)(i - 128);
    float arg = PI_F * 6.0f * x * (1.0f / 512.0f);
    float t = BETA2_F - arg * arg;
    float st = sqrtf(t);
    return 2.0f * st * __expf(-st);
}

// Branchless Kaiser-Bessel weight, large-x asymptotic i0 (3 transcendentals).
__device__ __forceinline__ float kbw(float u) {
    float t = 1.0f - u * u * (1.0f / 9.0f);
    float x = BETA_F * sqrtf(fmaxf(t, 0.0f));
    float xc = fmaxf(x, 0.35f);
    float R = __builtin_amdgcn_rsqf(xc);
    float R2 = R * R;
    float q = R * (0.39894228f + R2 * (0.04986779f + R2 * 0.02804702f));
    float w = __expf(xc) * q;
    return (t > 0.0f) ? w : 0.0f;
}

// DPP quad_perm cross-lane (no DS pipe)
template<int CTRL>
__device__ __forceinline__ float qdpp(float v) {
    int r = __builtin_amdgcn_mov_dpp(__float_as_int(v), CTRL, 0xF, 0xF, true);
    return __int_as_float(r);
}

__device__ __forceinline__ float2 cadd(float2 a, float2 b){ return make_float2(a.x+b.x, a.y+b.y); }
__device__ __forceinline__ float2 csub(float2 a, float2 b){ return make_float2(a.x-b.x, a.y-b.y); }
__device__ __forceinline__ float2 cmul(float2 a, float2 b){ return make_float2(a.x*b.x-a.y*b.y, a.x*b.y+a.y*b.x); }
__device__ __forceinline__ float2 mul_negi(float2 a){ return make_float2(a.y, -a.x); }
__device__ __forceinline__ float2 mul_posi(float2 a){ return make_float2(-a.y, a.x); }
__device__ __forceinline__ float2 mul_w81(float2 a){ return make_float2(RSQ2*(a.x+a.y), RSQ2*(a.y-a.x)); }
__device__ __forceinline__ float2 mul_w83(float2 a){ return make_float2(RSQ2*(a.y-a.x), -RSQ2*(a.x+a.y)); }

__device__ __forceinline__ void dft8_combine(float2 E0, float2 E1, float2 E2, float2 E3,
                                             float2 O0, float2 O1, float2 O2, float2 O3,
                                             float2* y) {
    float2 c1 = mul_w81(O1), c2 = mul_negi(O2), c3 = mul_w83(O3);
    y[0] = cadd(E0, O0); y[4] = csub(E0, O0);
    y[1] = cadd(E1, c1); y[5] = csub(E1, c1);
    y[2] = cadd(E2, c2); y[6] = csub(E2, c2);
    y[3] = cadd(E3, c3); y[7] = csub(E3, c3);
}

__device__ __forceinline__ void dft8(const float2* x, float2* y) {
    float2 a0=x[0], a1=x[2], a2=x[4], a3=x[6];
    float2 b0=x[1], b1=x[3], b2=x[5], b3=x[7];
    float2 ta0=cadd(a0,a2), ta1=csub(a0,a2), ta2=cadd(a1,a3), ta3=csub(a1,a3);
    float2 E0=cadd(ta0,ta2), E2=csub(ta0,ta2);
    float2 E1=cadd(ta1, mul_negi(ta3)), E3=cadd(ta1, mul_posi(ta3));
    float2 tb0=cadd(b0,b2), tb1=csub(b0,b2), tb2=cadd(b1,b3), tb3=csub(b1,b3);
    float2 O0=cadd(tb0,tb2), O2=csub(tb0,tb2);
    float2 O1=cadd(tb1, mul_negi(tb3)), O3=cadd(tb1, mul_posi(tb3));
    dft8_combine(E0,E1,E2,E3,O0,O1,O2,O3,y);
}

__device__ __forceinline__ void dft8_pruned(float2 x0, float2 x1, float2 x6, float2 x7, float2* y) {
    float2 E0 = cadd(x0, x6), E2 = csub(x0, x6);
    float2 E1 = cadd(x0, mul_posi(x6)), E3 = cadd(x0, mul_negi(x6));
    float2 O0 = cadd(x1, x7), O2 = csub(x1, x7);
    float2 O1 = cadd(x1, mul_posi(x7)), O3 = cadd(x1, mul_negi(x7));
    dft8_combine(E0,E1,E2,E3,O0,O1,O2,O3,y);
}

template<int S>
__device__ __forceinline__ void twiddle8(int t, float2* y) {
    if (S < 2) {
        int j = (S == 0) ? t : (t >> 3);
        const float scale = (S == 0) ? (-2.0f*PI_F/512.0f) : (-2.0f*PI_F/64.0f);
        float theta = scale * (float)j;
        float sn, cs;
        __sincosf(theta, &sn, &cs);              // sin FIRST, cos second
        float2 w = make_float2(cs, sn), wq = w;
        y[1] = cmul(y[1], wq);
        #pragma unroll
        for (int q = 2; q < 8; ++q) { wq = cmul(wq, w); y[q] = cmul(y[q], wq); }
    }
}

// ----- pair-cooperative half-butterfly primitives (pass 1, 128 thr/row) ---

__device__ __forceinline__ float2 pswap(float2 v) {
    return make_float2(qdpp<0xB1>(v.x), qdpp<0xB1>(v.y));
}

__device__ __forceinline__ void dft8_half(const float2* v, float2* EO) {
    float2 t0 = cadd(v[0], v[2]), t1 = csub(v[0], v[2]);
    float2 t2 = cadd(v[1], v[3]), t3 = csub(v[1], v[3]);
    EO[0] = cadd(t0, t2); EO[2] = csub(t0, t2);
    EO[1] = cadd(t1, mul_negi(t3)); EO[3] = cadd(t1, mul_posi(t3));
}

__device__ __forceinline__ void dft8p_half(float2 u0, float2 u1, float2* EO) {
    EO[0] = cadd(u0, u1); EO[2] = csub(u0, u1);
    EO[1] = cadd(u0, mul_posi(u1)); EO[3] = cadd(u0, mul_negi(u1));
}

__device__ __forceinline__ void combine_half(int h, const float2* V, float2* y) {
    float2 P0 = pswap(V[0]), P1 = pswap(V[1]), P2 = pswap(V[2]), P3 = pswap(V[3]);
    float2 E0 = h ? P0 : V[0], O0 = h ? V[0] : P0;
    float2 E1 = h ? P1 : V[1], O1 = h ? V[1] : P1;
    float2 E2 = h ? P2 : V[2], O2 = h ? V[2] : P2;
    float2 E3 = h ? P3 : V[3], O3 = h ? V[3] : P3;
    float2 c1 = mul_w81(O1), c2 = mul_negi(O2), c3 = mul_w83(O3);
    float s = h ? -1.0f : 1.0f;
    y[0] = make_float2(fmaf(s, O0.x, E0.x), fmaf(s, O0.y, E0.y));
    y[1] = make_float2(fmaf(s, c1.x, E1.x), fmaf(s, c1.y, E1.y));
    y[2] = make_float2(fmaf(s, c2.x, E2.x), fmaf(s, c2.y, E2.y));
    y[3] = make_float2(fmaf(s, c3.x, E3.x), fmaf(s, c3.y, E3.y));
}

__device__ __forceinline__ void twiddle4h(int jidx, float scale, int h, float2* y) {
    float theta = scale * (float)jidx;
    float sn, cs;
    __sincosf(theta, &sn, &cs);                  // sin FIRST, cos second
    float2 w = make_float2(cs, sn);
    float2 w2 = cmul(w, w);
    float2 w4 = cmul(w2, w2);
    float2 m = h ? w4 : make_float2(1.0f, 0.0f);
    y[0] = cmul(y[0], m);
    float2 wq = cmul(m, w); y[1] = cmul(y[1], wq);
    wq = cmul(wq, w);       y[2] = cmul(y[2], wq);
    wq = cmul(wq, w);       y[3] = cmul(y[3], wq);
}

// ---------------------------------------------------------------- pass 1
// Pair-cooperative row FFT (r4, verified) + cursor zeroing (block 0).
__global__ __launch_bounds__(256) void pass1_rowfft(const float* __restrict__ image,
                                                    float2* __restrict__ T,
                                                    int* __restrict__ cursors) {
    __shared__ float2 sm[2][2][578];
    int tid = threadIdx.x;
    if (blockIdx.x == 0) {
        for (int z = tid; z < 1024; z += 256) cursors[z] = 0;
    }
    int r = tid >> 7;                               // row within block {0,1}
    int tt = tid & 127;
    int h = tt & 1;                                 // butterfly half (E/O)
    int b = tt >> 1;                                // butterfly index 0..63
    int blk = blockIdx.x;
    int p = blk & 3;                                // batch pair 0..3
    int g = blk >> 2;                               // 0..127
    int rp = (g << 1) + r;                          // compact row 0..255
    int y = (rp < 128) ? rp : (rp + 256);
    int iy = (y < 128) ? (y + 128) : (y - 384);
    float ay = apod(iy);
    const float* irow0 = image + ((size_t)((2 * p)     * NSZ + iy)) * NSZ;
    const float* irow1 = image + ((size_t)((2 * p + 1) * NSZ + iy)) * NSZ;

    float2 y4[4];
    {
        int iA = h ? (b + 192) : (b + 128);
        int iB = h ? (b + 64)  : b;
        float wA = ay * apod(iA), wB = ay * apod(iB);
        float2 u0 = make_float2(irow0[iA] * wA, irow1[iA] * wA);
        float2 u1 = make_float2(irow0[iB] * wB, irow1[iB] * wB);
        float2 EO[4];
        dft8p_half(u0, u1, EO);
        combine_half(h, EO, y4);
        twiddle4h(b, -2.0f * PI_F / 512.0f, h, y4);
    }
    float2* A  = sm[0][r];
    float2* Bf = sm[1][r];
    #pragma unroll
    for (int qq = 0; qq < 4; ++qq) A[PADIDX((b << 3) + (h << 2) + qq)] = y4[qq];
    __syncthreads();
    {
        float2 v[4];
        #pragma unroll
        for (int i = 0; i < 4; ++i) v[i] = A[PADIDX(b + (((i << 1) + h) << 6))];
        float2 EO[4];
        dft8_half(v, EO);
        combine_half(h, EO, y4);
        twiddle4h(b >> 3, -2.0f * PI_F / 64.0f, h, y4);
        int base = (b & 7) + ((b >> 3) << 6);
        #pragma unroll
        for (int qq = 0; qq < 4; ++qq) Bf[PADIDX(base + (((h << 2) + qq) << 3))] = y4[qq];
    }
    __syncthreads();
    {
        float2 v[4];
        #pragma unroll
        for (int i = 0; i < 4; ++i) v[i] = Bf[PADIDX(b + (((i << 1) + h) << 6))];
        float2 EO[4];
        dft8_half(v, EO);
        combine_half(h, EO, y4);
        float2* Trow = T + (((size_t)(p << 8) + rp) << 9);
        #pragma unroll
        for (int qq = 0; qq < 4; ++qq) Trow[b + (((h << 2) + qq) << 6)] = y4[qq];
    }
}

// ---------------------------------------------------------------- pass 2
// blocks [0,256): column FFT + Hermitian unpack (verified, unchanged math).
// blocks [256,512): LDS-aggregated counting-sort scatter:
//   histogram (LDS atomics) → 128 global atomics/block (chunk reserve) →
//   LDS reorder by band → slot-ordered copy-out (runs of ~32 float4/band).
// Band order within a slice is nondeterministic but each point's out[m]
// is computed independently in pass 3 → output is order-invariant.
__global__ __launch_bounds__(256) void pass2_colfft(const float2* __restrict__ T,
                                                    float2* __restrict__ kgrid,
                                                    const float* __restrict__ ktraj,
                                                    const float* __restrict__ dcf,
                                                    int* __restrict__ cursors,
                                                    float4* __restrict__ sortedpt) {
    // union carve: FFT branch needs 36,992 B; scatter needs 67,584 B.
    __shared__ float4 smemBuf[4224];                // 67,584 B → 2 blocks/CU
    int tid = threadIdx.x;
    int blk = blockIdx.x;

    if (blk >= 256) {
        // ---------------- LDS-aggregated scatter
        int u = blk - 256;
        int bs = u >> 5, seg = u & 31;              // 8 batches × 32 segs × 4096
        const float SCALE = (float)GSZ / (2.0f * PI_F);
        const float* kt1 = ktraj + (size_t)(bs * 2) * MPTS;
        const float* kt2 = kt1 + MPTS;
        const float* dcfb = dcf + ((size_t)bs << 17);
        int* cur = cursors + (bs << 7);
        float4* sp = sortedpt + ((size_t)bs << 18); // 128 bands * 2048 slots

        float4* pts = smemBuf;                      // [4096]
        int* hist = (int*)(smemBuf + 4096);         // [128]
        int* lofs = hist + 128;                     // [128]
        int* gbase = hist + 256;                    // [128]
        int* lcur = hist + 384;                     // [128]

        if (tid < 128) hist[tid] = 0;
        __syncthreads();

        // phase 1: load 16 pts/thread, LDS histogram
        float t1v[16], t2v[16], dv[16];
        #pragma unroll
        for (int k = 0; k < 16; ++k) {
            int m = (seg << 12) + (k << 8) + tid;
            t1v[k] = kt1[m] * SCALE;
            t2v[k] = kt2[m] * SCALE;
            dv[k]  = dcfb[m];
            int key = (((int)floorf(t1v[k])) & 511) >> 2;
            atomicAdd(&hist[key], 1);
        }
        __syncthreads();

        // phase 2: serial prefix (128 adds) + 128 global atomics (chunk reserve)
        if (tid == 0) {
            int s = 0;
            #pragma unroll 8
            for (int i = 0; i < 128; ++i) { lofs[i] = s; s += hist[i]; }
        }
        if (tid < 128) { gbase[tid] = atomicAdd(cur + tid, hist[tid]); lcur[tid] = 0; }
        __syncthreads();

        // phase 3: reorder into LDS by band (band packed into index word)
        #pragma unroll
        for (int k = 0; k < 16; ++k) {
            int m = (seg << 12) + (k << 8) + tid;
            int key = (((int)floorf(t1v[k])) & 511) >> 2;
            int loc = atomicAdd(&lcur[key], 1);
            pts[lofs[key] + loc] =
                make_float4(t1v[k], t2v[k], dv[k], __int_as_float((key << 17) | m));
        }
        __syncthreads();

        // phase 4: slot-ordered copy-out — consecutive slots share a band
        // (~32-slot runs) → coalesced ~512B bursts instead of random lines
        #pragma unroll
        for (int k = 0; k < 16; ++k) {
            int s = (k << 8) + tid;
            float4 p = pts[s];
            int w = __float_as_int(p.w);
            int key = w >> 17;
            int m = w & 0x1FFFF;
            int gpos = gbase[key] + (s - lofs[key]);
            if (gpos < 2048)
                sp[((size_t)key << 11) + gpos] =
                    make_float4(p.x, p.y, p.z, __int_as_float(m));
        }
        return;
    }

    float2 (*B)[578] = reinterpret_cast<float2(*)[578]>(smemBuf);
    int p = blk & 3;                                // batch pair
    int g = blk >> 2;                               // 0..63 col group
    const float2* Tb = T + ((size_t)p << 17);       // 256*512 per pair
    float2* Kb0 = kgrid + ((size_t)(2 * p) << 18);
    float2* Kb1 = Kb0 + ((size_t)1 << 18);

    #define COLG(c) ((g > 0) ? (((c) < 4) ? ((g << 2) + (c)) : (505 - (g << 2) + (c))) \
                             : (((c) < 4) ? (c) : (((c) == 7) ? 256 : (505 + (c)))))

    {
        int c = tid & 7, r0 = tid >> 3;             // r0 0..31
        int colg = COLG(c);
        #pragma unroll
        for (int k = 0; k < 8; ++k) {
            int rr = r0 + (k << 5);
            B[c][PADIDX(rr)] = Tb[((size_t)rr << 9) + colg];
        }
    }
    __syncthreads();
    int t = tid & 63;
    int c0 = tid >> 6;                              // slots c0 and c0+4
    float2* Ba = B[c0];
    float2* Bb = B[c0 + 4];
    float2 ya[8], yb[8];
    {
        float2 a0 = Ba[PADIDX(t)],       a1 = Ba[PADIDX(t + 64)];
        float2 a6 = Ba[PADIDX(t + 128)], a7 = Ba[PADIDX(t + 192)];
        float2 b0 = Bb[PADIDX(t)],       b1 = Bb[PADIDX(t + 64)];
        float2 b6 = Bb[PADIDX(t + 128)], b7 = Bb[PADIDX(t + 192)];
        dft8_pruned(a0, a1, a6, a7, ya); twiddle8<0>(t, ya);
        dft8_pruned(b0, b1, b6, b7, yb); twiddle8<0>(t, yb);
    }
    __syncthreads();
    #pragma unroll
    for (int q = 0; q < 8; ++q) {
        Ba[PADIDX((t << 3) + q)] = ya[q];
        Bb[PADIDX((t << 3) + q)] = yb[q];
    }
    __syncthreads();
    {
        float2 xa[8], xb[8];
        #pragma unroll
        for (int pp = 0; pp < 8; ++pp) { xa[pp] = Ba[PADIDX(t + (pp << 6))]; xb[pp] = Bb[PADIDX(t + (pp << 6))]; }
        dft8(xa, ya); twiddle8<1>(t, ya);
        dft8(xb, yb); twiddle8<1>(t, yb);
    }
    __syncthreads();
    {
        int j = t >> 3, k = t & 7, base = k + (j << 6);
        #pragma unroll
        for (int q = 0; q < 8; ++q) {
            Ba[PADIDX(base + (q << 3))] = ya[q];
            Bb[PADIDX(base + (q << 3))] = yb[q];
        }
    }
    __syncthreads();
    {
        float2 xa[8], xb[8];
        #pragma unroll
        for (int pp = 0; pp < 8; ++pp) { xa[pp] = Ba[PADIDX(t + (pp << 6))]; xb[pp] = Bb[PADIDX(t + (pp << 6))]; }
        dft8(xa, ya);
        dft8(xb, yb);
    }
    __syncthreads();
    #pragma unroll
    for (int q = 0; q < 8; ++q) {
        Ba[PADIDX(t + (q << 6))] = ya[q];
        Bb[PADIDX(t + (q << 6))] = yb[q];
    }
    __syncthreads();
    {
        int c = tid & 7, r0 = tid >> 3;
        int colg = COLG(c);
        int mc = 7 - c;
        if (g == 0) { if (c == 0) mc = 0; else if (c == 7) mc = 7; }
        #pragma unroll
        for (int k = 0; k < 16; ++k) {
            int rr = r0 + (k << 5);
            int mr = (512 - rr) & 511;
            float2 Z = B[c][PADIDX(rr)];
            float2 M = B[mc][PADIDX(mr)];
            float2 K0 = make_float2(0.5f * (Z.x + M.x), 0.5f * (Z.y - M.y));
            float2 K1 = make_float2(0.5f * (Z.y + M.y), 0.5f * (M.x - Z.x));
            size_t off = ((size_t)rr << 9) + colg;
            Kb0[off] = K0;
            Kb1[off] = K1;
        }
    }
    #undef COLG
}

// ---------------------------------------------------------------- pass 3
// Band-local KB gather (r5, verified): block = (batch, 4-row band).
__global__ __launch_bounds__(256) void interp_kb(const float2* __restrict__ kgrid,
                                                 const int* __restrict__ cursors,
                                                 const float4* __restrict__ sortedpt,
                                                 float* __restrict__ out) {
    __shared__ float lds[9 * 1028];                 // 37,008 B → 4 blocks/CU
    int tid = threadIdx.x;
    int blk = blockIdx.x;
    int b = blk & 7;                                // XCD affinity on batch
    int band = blk >> 3;                            // 0..127
    int j = tid & 3;                                // lane within quad
    int q = tid >> 2;                               // quad 0..63
    int j2 = j << 1;
    float fjm2 = (float)(j - 2), fjp2 = (float)(j + 2);

    int cnt = cursors[(b << 7) + band];
    cnt = (cnt > 2048) ? 2048 : cnt;
    if (cnt == 0) return;                           // block-uniform, pre-sync

    // ---- stage 9 rows of kgrid[b] (global rows band*4-2 .. +6, mod 512)
    const float2* Kb = kgrid + ((size_t)b << 18);
    #pragma unroll
    for (int r = 0; r < 9; ++r) {
        int gr = ((band << 2) - 2 + r) & 511;
        const float4* src = (const float4*)(Kb + ((size_t)gr << 9));
        *(float4*)(lds + r * 1028 + (tid << 2)) = src[tid];
    }
    __syncthreads();

    const float4* sp = sortedpt + ((size_t)b << 18) + ((size_t)band << 11);
    float* out_re = out + ((size_t)b << 17);
    float* out_im = out_re + (size_t)NBATCH * MPTS;

    int iters = (cnt + 63) >> 6;
    for (int it = 0; it < iters; ++it) {
        int pidx = (it << 6) + q;
        bool valid = pidx < cnt;
        float4 pt = sp[valid ? pidx : 0];           // quad-uniform address
        float tm1 = pt.x, tm2 = pt.y, dd = pt.z;
        int m = __float_as_int(pt.w);

        float f1 = floorf(tm1), f2 = floorf(tm2);
        int if1 = (int)f1, if2 = (int)f2;
        int e0 = (if2 - 2) & ~1;                    // even base col
        int cpair = (e0 + j2) & 511;                // even → pair in-row
        int lr = (if1 & 511) - (band << 2);         // 0..3 (band-local row)

        // ---- weights (identical math to verified kernel)
        float u2 = tm2 - (float)(e0 + j2);
        float w2a = kbw(u2);
        float w2b = kbw(u2 - 1.0f);
        float fr1 = tm1 - f1;
        float w1A = kbw(fr1 - fjm2);
        float w1B = kbw(fr1 - fjp2);
        float w0_ = qdpp<0x00>(w1A);
        float w1_ = qdpp<0x55>(w1A);
        float w2_ = qdpp<0xAA>(w1A);
        float w3_ = qdpp<0xFF>(w1A);
        float w4_ = qdpp<0x00>(w1B);
        float w5_ = qdpp<0x55>(w1B);

        // ---- 6 row reads from LDS (16B aligned: cpair even, stride 4112B)
        const float* lp = lds + (cpair << 1);
        f32x4 v0 = *(const f32x4*)(lp + (lr + 0) * 1028);
        f32x4 v1 = *(const f32x4*)(lp + (lr + 1) * 1028);
        f32x4 v2 = *(const f32x4*)(lp + (lr + 2) * 1028);
        f32x4 v3 = *(const f32x4*)(lp + (lr + 3) * 1028);
        f32x4 v4 = *(const f32x4*)(lp + (lr + 4) * 1028);
        f32x4 v5 = *(const f32x4*)(lp + (lr + 5) * 1028);

        // ---- fma chain (bit-identical ordering to verified kernel)
        float c0re = w0_ * v0.x, c0im = w0_ * v0.y;
        float c1re = w0_ * v0.z, c1im = w0_ * v0.w;
        c0re = fmaf(w1_, v1.x, c0re); c0im = fmaf(w1_, v1.y, c0im);
        c1re = fmaf(w1_, v1.z, c1re); c1im = fmaf(w1_, v1.w, c1im);
        c0re = fmaf(w2_, v2.x, c0re); c0im = fmaf(w2_, v2.y, c0im);
        c1re = fmaf(w2_, v2.z, c1re); c1im = fmaf(w2_, v2.w, c1im);
        c0re = fmaf(w3_, v3.x, c0re); c0im = fmaf(w3_, v3.y, c0im);
        c1re = fmaf(w3_, v3.z, c1re); c1im = fmaf(w3_, v3.w, c1im);
        c0re = fmaf(w4_, v4.x, c0re); c0im = fmaf(w4_, v4.y, c0im);
        c1re = fmaf(w4_, v4.z, c1re); c1im = fmaf(w4_, v4.w, c1im);
        c0re = fmaf(w5_, v5.x, c0re); c0im = fmaf(w5_, v5.y, c0im);
        c1re = fmaf(w5_, v5.z, c1re); c1im = fmaf(w5_, v5.w, c1im);
        float p_re = fmaf(w2a, c0re, w2b * c1re);
        float p_im = fmaf(w2a, c0im, w2b * c1im);
        p_re += qdpp<0xB1>(p_re); p_re += qdpp<0x4E>(p_re);
        p_im += qdpp<0xB1>(p_im); p_im += qdpp<0x4E>(p_im);

        if (valid) {
            if (j == 0) out_re[m] = p_re * dd;
            else if (j == 1) out_im[m] = p_im * dd;
        }
    }
}

// ---------------------------------------------------------------- launch

extern "C" void kernel_launch(void* const* d_in, const int* in_sizes, int n_in,
                              void* d_out, int out_size, void* d_ws, size_t ws_size,
                              hipStream_t stream) {
    const float* image = (const float*)d_in[0];   // (8,256,256) f32
    const float* ktraj = (const float*)d_in[1];   // (8,2,131072) f32
    const float* dcf   = (const float*)d_in[2];   // (8,131072) f32
    float* out = (float*)d_out;                   // (2,8,131072) f32

    // workspace layout (bytes):
    //   T        @ 0          4,194,304   (4 pairs * 256*512 c64)
    //   kgrid    @ 4,194,304  16,777,216  (8 * 512*512 c64)
    //   cursors  @ 20,971,520 4,096       (8 * 128 int)
    //   sortedpt @ 20,975,616 33,554,432  (8 * 128 bands * 2048 * float4)
    float2* T        = (float2*)d_ws;
    float2* kgrid    = T + (size_t)4 * 256 * GSZ;
    int*    cursors  = (int*)((char*)d_ws + 20971520);
    float4* sortedpt = (float4*)((char*)d_ws + 20975616);

    pass1_rowfft<<<512, 256, 0, stream>>>(image, T, cursors);
    pass2_colfft<<<512, 256, 0, stream>>>(T, kgrid, ktraj, dcf, cursors, sortedpt);
    interp_kb<<<1024, 256, 0, stream>>>(kgrid, cursors, sortedpt, out);
}

// Round 7
// 121.185 us; speedup vs baseline: 1.7866x; 1.0173x over previous
//
#include <hip/hip_runtime.h>
#include <math.h>

#define GSZ 512
#define NSZ 256
#define NBATCH 8
#define MPTS 131072
#define PI_F 3.14159265358979f
#define BETA_F 13.8551004f
#define BETA2_F (BETA_F * BETA_F)
#define RSQ2 0.70710678f
// LDS pad: +1 float2 every 8 → strided radix-8 access conflict-reduced
#define PADIDX(i) ((i) + ((i) >> 3))

typedef float f32x4 __attribute__((ext_vector_type(4)));

// ---------------------------------------------------------------- helpers

// Exact asymptotic de-apodization: st ∈ [13.03, 13.855] so
// st/sinh(st) = 2·st·e^(−st)·(1+O(e^(−2st))), rel err < 5e-12.
__device__ __forceinline__ float apod(int i) {
    float x = (float)(i - 128);
    float arg = PI_F * 6.0f * x * (1.0f / 512.0f);
    float t = BETA2_F - arg * arg;
    float st = sqrtf(t);
    return 2.0f * st * __expf(-st);
}

// Branchless Kaiser-Bessel weight, large-x asymptotic i0 (3 transcendentals).
__device__ __forceinline__ float kbw(float u) {
    float t = 1.0f - u * u * (1.0f / 9.0f);
    float x = BETA_F * sqrtf(fmaxf(t, 0.0f));
    float xc = fmaxf(x, 0.35f);
    float R = __builtin_amdgcn_rsqf(xc);
    float R2 = R * R;
    float q = R * (0.39894228f + R2 * (0.04986779f + R2 * 0.02804702f));
    float w = __expf(xc) * q;
    return (t > 0.0f) ? w : 0.0f;
}

// DPP quad_perm cross-lane (no DS pipe)
template<int CTRL>
__device__ __forceinline__ float qdpp(float v) {
    int r = __builtin_amdgcn_mov_dpp(__float_as_int(v), CTRL, 0xF, 0xF, true);
    return __int_as_float(r);
}

__device__ __forceinline__ float2 cadd(float2 a, float2 b){ return make_float2(a.x+b.x, a.y+b.y); }
__device__ __forceinline__ float2 csub(float2 a, float2 b){ return make_float2(a.x-b.x, a.y-b.y); }
__device__ __forceinline__ float2 cmul(float2 a, float2 b){ return make_float2(a.x*b.x-a.y*b.y, a.x*b.y+a.y*b.x); }
__device__ __forceinline__ float2 mul_negi(float2 a){ return make_float2(a.y, -a.x); }
__device__ __forceinline__ float2 mul_posi(float2 a){ return make_float2(-a.y, a.x); }
__device__ __forceinline__ float2 mul_w81(float2 a){ return make_float2(RSQ2*(a.x+a.y), RSQ2*(a.y-a.x)); }
__device__ __forceinline__ float2 mul_w83(float2 a){ return make_float2(RSQ2*(a.y-a.x), -RSQ2*(a.x+a.y)); }

__device__ __forceinline__ void dft8_combine(float2 E0, float2 E1, float2 E2, float2 E3,
                                             float2 O0, float2 O1, float2 O2, float2 O3,
                                             float2* y) {
    float2 c1 = mul_w81(O1), c2 = mul_negi(O2), c3 = mul_w83(O3);
    y[0] = cadd(E0, O0); y[4] = csub(E0, O0);
    y[1] = cadd(E1, c1); y[5] = csub(E1, c1);
    y[2] = cadd(E2, c2); y[6] = csub(E2, c2);
    y[3] = cadd(E3, c3); y[7] = csub(E3, c3);
}

__device__ __forceinline__ void dft8(const float2* x, float2* y) {
    float2 a0=x[0], a1=x[2], a2=x[4], a3=x[6];
    float2 b0=x[1], b1=x[3], b2=x[5], b3=x[7];
    float2 ta0=cadd(a0,a2), ta1=csub(a0,a2), ta2=cadd(a1,a3), ta3=csub(a1,a3);
    float2 E0=cadd(ta0,ta2), E2=csub(ta0,ta2);
    float2 E1=cadd(ta1, mul_negi(ta3)), E3=cadd(ta1, mul_posi(ta3));
    float2 tb0=cadd(b0,b2), tb1=csub(b0,b2), tb2=cadd(b1,b3), tb3=csub(b1,b3);
    float2 O0=cadd(tb0,tb2), O2=csub(tb0,tb2);
    float2 O1=cadd(tb1, mul_negi(tb3)), O3=cadd(tb1, mul_posi(tb3));
    dft8_combine(E0,E1,E2,E3,O0,O1,O2,O3,y);
}

__device__ __forceinline__ void dft8_pruned(float2 x0, float2 x1, float2 x6, float2 x7, float2* y) {
    float2 E0 = cadd(x0, x6), E2 = csub(x0, x6);
    float2 E1 = cadd(x0, mul_posi(x6)), E3 = cadd(x0, mul_negi(x6));
    float2 O0 = cadd(x1, x7), O2 = csub(x1, x7);
    float2 O1 = cadd(x1, mul_posi(x7)), O3 = cadd(x1, mul_negi(x7));
    dft8_combine(E0,E1,E2,E3,O0,O1,O2,O3,y);
}

template<int S>
__device__ __forceinline__ void twiddle8(int t, float2* y) {
    if (S < 2) {
        int j = (S == 0) ? t : (t >> 3);
        const float scale = (S == 0) ? (-2.0f*PI_F/512.0f) : (-2.0f*PI_F/64.0f);
        float theta = scale * (float)j;
        float sn, cs;
        __sincosf(theta, &sn, &cs);              // sin FIRST, cos second
        float2 w = make_float2(cs, sn), wq = w;
        y[1] = cmul(y[1], wq);
        #pragma unroll
        for (int q = 2; q < 8; ++q) { wq = cmul(wq, w); y[q] = cmul(y[q], wq); }
    }
}

// ----- pair-cooperative half-butterfly primitives (pass 1, 128 thr/row) ---

__device__ __forceinline__ float2 pswap(float2 v) {
    return make_float2(qdpp<0xB1>(v.x), qdpp<0xB1>(v.y));
}

__device__ __forceinline__ void dft8_half(const float2* v, float2* EO) {
    float2 t0 = cadd(v[0], v[2]), t1 = csub(v[0], v[2]);
    float2 t2 = cadd(v[1], v[3]), t3 = csub(v[1], v[3]);
    EO[0] = cadd(t0, t2); EO[2] = csub(t0, t2);
    EO[1] = cadd(t1, mul_negi(t3)); EO[3] = cadd(t1, mul_posi(t3));
}

__device__ __forceinline__ void dft8p_half(float2 u0, float2 u1, float2* EO) {
    EO[0] = cadd(u0, u1); EO[2] = csub(u0, u1);
    EO[1] = cadd(u0, mul_posi(u1)); EO[3] = cadd(u0, mul_negi(u1));
}

__device__ __forceinline__ void combine_half(int h, const float2* V, float2* y) {
    float2 P0 = pswap(V[0]), P1 = pswap(V[1]), P2 = pswap(V[2]), P3 = pswap(V[3]);
    float2 E0 = h ? P0 : V[0], O0 = h ? V[0] : P0;
    float2 E1 = h ? P1 : V[1], O1 = h ? V[1] : P1;
    float2 E2 = h ? P2 : V[2], O2 = h ? V[2] : P2;
    float2 E3 = h ? P3 : V[3], O3 = h ? V[3] : P3;
    float2 c1 = mul_w81(O1), c2 = mul_negi(O2), c3 = mul_w83(O3);
    float s = h ? -1.0f : 1.0f;
    y[0] = make_float2(fmaf(s, O0.x, E0.x), fmaf(s, O0.y, E0.y));
    y[1] = make_float2(fmaf(s, c1.x, E1.x), fmaf(s, c1.y, E1.y));
    y[2] = make_float2(fmaf(s, c2.x, E2.x), fmaf(s, c2.y, E2.y));
    y[3] = make_float2(fmaf(s, c3.x, E3.x), fmaf(s, c3.y, E3.y));
}

__device__ __forceinline__ void twiddle4h(int jidx, float scale, int h, float2* y) {
    float theta = scale * (float)jidx;
    float sn, cs;
    __sincosf(theta, &sn, &cs);                  // sin FIRST, cos second
    float2 w = make_float2(cs, sn);
    float2 w2 = cmul(w, w);
    float2 w4 = cmul(w2, w2);
    float2 m = h ? w4 : make_float2(1.0f, 0.0f);
    y[0] = cmul(y[0], m);
    float2 wq = cmul(m, w); y[1] = cmul(y[1], wq);
    wq = cmul(wq, w);       y[2] = cmul(y[2], wq);
    wq = cmul(wq, w);       y[3] = cmul(y[3], wq);
}

// ---------------------------------------------------------------- pass 1
// Pair-cooperative row FFT (r4, verified) + cursor zeroing (block 0).
__global__ __launch_bounds__(256) void pass1_rowfft(const float* __restrict__ image,
                                                    float2* __restrict__ T,
                                                    int* __restrict__ cursors) {
    __shared__ float2 sm[2][2][578];
    int tid = threadIdx.x;
    if (blockIdx.x == 0) {
        for (int z = tid; z < 1024; z += 256) cursors[z] = 0;
    }
    int r = tid >> 7;                               // row within block {0,1}
    int tt = tid & 127;
    int h = tt & 1;                                 // butterfly half (E/O)
    int b = tt >> 1;                                // butterfly index 0..63
    int blk = blockIdx.x;
    int p = blk & 3;                                // batch pair 0..3
    int g = blk >> 2;                               // 0..127
    int rp = (g << 1) + r;                          // compact row 0..255
    int y = (rp < 128) ? rp : (rp + 256);
    int iy = (y < 128) ? (y + 128) : (y - 384);
    float ay = apod(iy);
    const float* irow0 = image + ((size_t)((2 * p)     * NSZ + iy)) * NSZ;
    const float* irow1 = image + ((size_t)((2 * p + 1) * NSZ + iy)) * NSZ;

    float2 y4[4];
    {
        int iA = h ? (b + 192) : (b + 128);
        int iB = h ? (b + 64)  : b;
        float wA = ay * apod(iA), wB = ay * apod(iB);
        float2 u0 = make_float2(irow0[iA] * wA, irow1[iA] * wA);
        float2 u1 = make_float2(irow0[iB] * wB, irow1[iB] * wB);
        float2 EO[4];
        dft8p_half(u0, u1, EO);
        combine_half(h, EO, y4);
        twiddle4h(b, -2.0f * PI_F / 512.0f, h, y4);
    }
    float2* A  = sm[0][r];
    float2* Bf = sm[1][r];
    #pragma unroll
    for (int qq = 0; qq < 4; ++qq) A[PADIDX((b << 3) + (h << 2) + qq)] = y4[qq];
    __syncthreads();
    {
        float2 v[4];
        #pragma unroll
        for (int i = 0; i < 4; ++i) v[i] = A[PADIDX(b + (((i << 1) + h) << 6))];
        float2 EO[4];
        dft8_half(v, EO);
        combine_half(h, EO, y4);
        twiddle4h(b >> 3, -2.0f * PI_F / 64.0f, h, y4);
        int base = (b & 7) + ((b >> 3) << 6);
        #pragma unroll
        for (int qq = 0; qq < 4; ++qq) Bf[PADIDX(base + (((h << 2) + qq) << 3))] = y4[qq];
    }
    __syncthreads();
    {
        float2 v[4];
        #pragma unroll
        for (int i = 0; i < 4; ++i) v[i] = Bf[PADIDX(b + (((i << 1) + h) << 6))];
        float2 EO[4];
        dft8_half(v, EO);
        combine_half(h, EO, y4);
        float2* Trow = T + (((size_t)(p << 8) + rp) << 9);
        #pragma unroll
        for (int qq = 0; qq < 4; ++qq) Trow[b + (((h << 2) + qq) << 6)] = y4[qq];
    }
}

// ---------------------------------------------------------------- pass 2
// blocks [0,256): column FFT + Hermitian unpack; output now TRANSPOSED:
//   kgridT[col][row] → each col is a contiguous run → per store instr each
//   col's lanes write 64B contiguous (full lines, was 32 scattered 8B lines).
// blocks [256,512): LDS-aggregated counting-sort scatter (r6, verified),
//   key switched to tm2 (cols) to match the transposed consumer.
__global__ __launch_bounds__(256) void pass2_colfft(const float2* __restrict__ T,
                                                    float2* __restrict__ kgridT,
                                                    const float* __restrict__ ktraj,
                                                    const float* __restrict__ dcf,
                                                    int* __restrict__ cursors,
                                                    float4* __restrict__ sortedpt) {
    // union carve: FFT branch needs 36,992 B; scatter needs 67,584 B.
    __shared__ float4 smemBuf[4224];                // 67,584 B → 2 blocks/CU
    int tid = threadIdx.x;
    int blk = blockIdx.x;

    if (blk >= 256) {
        // ---------------- LDS-aggregated scatter (key = tm2 band)
        int u = blk - 256;
        int bs = u >> 5, seg = u & 31;              // 8 batches × 32 segs × 4096
        const float SCALE = (float)GSZ / (2.0f * PI_F);
        const float* kt1 = ktraj + (size_t)(bs * 2) * MPTS;
        const float* kt2 = kt1 + MPTS;
        const float* dcfb = dcf + ((size_t)bs << 17);
        int* cur = cursors + (bs << 7);
        float4* sp = sortedpt + ((size_t)bs << 18); // 128 bands * 2048 slots

        float4* pts = smemBuf;                      // [4096]
        int* hist = (int*)(smemBuf + 4096);         // [128]
        int* lofs = hist + 128;                     // [128]
        int* gbase = hist + 256;                    // [128]
        int* lcur = hist + 384;                     // [128]

        if (tid < 128) hist[tid] = 0;
        __syncthreads();

        // phase 1: load 16 pts/thread, LDS histogram
        float t1v[16], t2v[16], dv[16];
        #pragma unroll
        for (int k = 0; k < 16; ++k) {
            int m = (seg << 12) + (k << 8) + tid;
            t1v[k] = kt1[m] * SCALE;
            t2v[k] = kt2[m] * SCALE;
            dv[k]  = dcfb[m];
            int key = (((int)floorf(t2v[k])) & 511) >> 2;
            atomicAdd(&hist[key], 1);
        }
        __syncthreads();

        // phase 2: serial prefix (128 adds) + 128 global atomics (chunk reserve)
        if (tid == 0) {
            int s = 0;
            #pragma unroll 8
            for (int i = 0; i < 128; ++i) { lofs[i] = s; s += hist[i]; }
        }
        if (tid < 128) { gbase[tid] = atomicAdd(cur + tid, hist[tid]); lcur[tid] = 0; }
        __syncthreads();

        // phase 3: reorder into LDS by band (band packed into index word)
        #pragma unroll
        for (int k = 0; k < 16; ++k) {
            int m = (seg << 12) + (k << 8) + tid;
            int key = (((int)floorf(t2v[k])) & 511) >> 2;
            int loc = atomicAdd(&lcur[key], 1);
            pts[lofs[key] + loc] =
                make_float4(t1v[k], t2v[k], dv[k], __int_as_float((key << 17) | m));
        }
        __syncthreads();

        // phase 4: slot-ordered copy-out — coalesced ~512B bursts per band
        #pragma unroll
        for (int k = 0; k < 16; ++k) {
            int s = (k << 8) + tid;
            float4 p = pts[s];
            int w = __float_as_int(p.w);
            int key = w >> 17;
            int m = w & 0x1FFFF;
            int gpos = gbase[key] + (s - lofs[key]);
            if (gpos < 2048)
                sp[((size_t)key << 11) + gpos] =
                    make_float4(p.x, p.y, p.z, __int_as_float(m));
        }
        return;
    }

    float2 (*B)[578] = reinterpret_cast<float2(*)[578]>(smemBuf);
    int p = blk & 3;                                // batch pair
    int g = blk >> 2;                               // 0..63 col group
    const float2* Tb = T + ((size_t)p << 17);       // 256*512 per pair
    float2* Kb0 = kgridT + ((size_t)(2 * p) << 18);
    float2* Kb1 = Kb0 + ((size_t)1 << 18);

    #define COLG(c) ((g > 0) ? (((c) < 4) ? ((g << 2) + (c)) : (505 - (g << 2) + (c))) \
                             : (((c) < 4) ? (c) : (((c) == 7) ? 256 : (505 + (c)))))

    {
        int c = tid & 7, r0 = tid >> 3;             // r0 0..31
        int colg = COLG(c);
        #pragma unroll
        for (int k = 0; k < 8; ++k) {
            int rr = r0 + (k << 5);
            B[c][PADIDX(rr)] = Tb[((size_t)rr << 9) + colg];
        }
    }
    __syncthreads();
    int t = tid & 63;
    int c0 = tid >> 6;                              // slots c0 and c0+4
    float2* Ba = B[c0];
    float2* Bb = B[c0 + 4];
    float2 ya[8], yb[8];
    {
        float2 a0 = Ba[PADIDX(t)],       a1 = Ba[PADIDX(t + 64)];
        float2 a6 = Ba[PADIDX(t + 128)], a7 = Ba[PADIDX(t + 192)];
        float2 b0 = Bb[PADIDX(t)],       b1 = Bb[PADIDX(t + 64)];
        float2 b6 = Bb[PADIDX(t + 128)], b7 = Bb[PADIDX(t + 192)];
        dft8_pruned(a0, a1, a6, a7, ya); twiddle8<0>(t, ya);
        dft8_pruned(b0, b1, b6, b7, yb); twiddle8<0>(t, yb);
    }
    __syncthreads();
    #pragma unroll
    for (int q = 0; q < 8; ++q) {
        Ba[PADIDX((t << 3) + q)] = ya[q];
        Bb[PADIDX((t << 3) + q)] = yb[q];
    }
    __syncthreads();
    {
        float2 xa[8], xb[8];
        #pragma unroll
        for (int pp = 0; pp < 8; ++pp) { xa[pp] = Ba[PADIDX(t + (pp << 6))]; xb[pp] = Bb[PADIDX(t + (pp << 6))]; }
        dft8(xa, ya); twiddle8<1>(t, ya);
        dft8(xb, yb); twiddle8<1>(t, yb);
    }
    __syncthreads();
    {
        int j = t >> 3, k = t & 7, base = k + (j << 6);
        #pragma unroll
        for (int q = 0; q < 8; ++q) {
            Ba[PADIDX(base + (q << 3))] = ya[q];
            Bb[PADIDX(base + (q << 3))] = yb[q];
        }
    }
    __syncthreads();
    {
        float2 xa[8], xb[8];
        #pragma unroll
        for (int pp = 0; pp < 8; ++pp) { xa[pp] = Ba[PADIDX(t + (pp << 6))]; xb[pp] = Bb[PADIDX(t + (pp << 6))]; }
        dft8(xa, ya);
        dft8(xb, yb);
    }
    __syncthreads();
    #pragma unroll
    for (int q = 0; q < 8; ++q) {
        Ba[PADIDX(t + (q << 6))] = ya[q];
        Bb[PADIDX(t + (q << 6))] = yb[q];
    }
    __syncthreads();
    {
        int c = tid & 7, r0 = tid >> 3;
        int colg = COLG(c);
        int mc = 7 - c;
        if (g == 0) { if (c == 0) mc = 0; else if (c == 7) mc = 7; }
        #pragma unroll
        for (int k = 0; k < 16; ++k) {
            int rr = r0 + (k << 5);
            int mr = (512 - rr) & 511;
            float2 Z = B[c][PADIDX(rr)];
            float2 M = B[mc][PADIDX(mr)];
            float2 K0 = make_float2(0.5f * (Z.x + M.x), 0.5f * (Z.y - M.y));
            float2 K1 = make_float2(0.5f * (Z.y + M.y), 0.5f * (M.x - Z.x));
            size_t off = ((size_t)colg << 9) + rr;   // TRANSPOSED: [col][row]
            Kb0[off] = K0;
            Kb1[off] = K1;
        }
    }
    #undef COLG
}

// ---------------------------------------------------------------- pass 3
// Band-local KB gather on the TRANSPOSED grid: block = (batch, 4-col band).
// Stage 9 contiguous kgridT rows (= 9 grid cols, 4+5 halo) into LDS —
// coalesced float4, byte-identical loop shape to r6. Per point the math is
// the exact mirror of the verified kernel: tm1↔tm2 swap roles — rows use
// the even-pair per-lane path, cols use the DPP-broadcast path.
__global__ __launch_bounds__(256) void interp_kb(const float2* __restrict__ kgridT,
                                                 const int* __restrict__ cursors,
                                                 const float4* __restrict__ sortedpt,
                                                 float* __restrict__ out) {
    __shared__ float lds[9 * 1028];                 // 37,008 B → 4 blocks/CU
    int tid = threadIdx.x;
    int blk = blockIdx.x;
    int b = blk & 7;                                // XCD affinity on batch
    int band = blk >> 3;                            // 0..127 (col bands)
    int j = tid & 3;                                // lane within quad
    int q = tid >> 2;                               // quad 0..63
    int j2 = j << 1;
    float fjm2 = (float)(j - 2), fjp2 = (float)(j + 2);

    int cnt = cursors[(b << 7) + band];
    cnt = (cnt > 2048) ? 2048 : cnt;
    if (cnt == 0) return;                           // block-uniform, pre-sync

    // ---- stage 9 kgridT rows (grid cols band*4-2 .. +6, mod 512)
    const float2* Kb = kgridT + ((size_t)b << 18);
    #pragma unroll
    for (int r = 0; r < 9; ++r) {
        int gc = ((band << 2) - 2 + r) & 511;
        const float4* src = (const float4*)(Kb + ((size_t)gc << 9));
        *(float4*)(lds + r * 1028 + (tid << 2)) = src[tid];
    }
    __syncthreads();

    const float4* sp = sortedpt + ((size_t)b << 18) + ((size_t)band << 11);
    float* out_re = out + ((size_t)b << 17);
    float* out_im = out_re + (size_t)NBATCH * MPTS;

    int iters = (cnt + 63) >> 6;
    for (int it = 0; it < iters; ++it) {
        int pidx = (it << 6) + q;
        bool valid = pidx < cnt;
        float4 pt = sp[valid ? pidx : 0];           // quad-uniform address
        float tm1 = pt.x, tm2 = pt.y, dd = pt.z;
        int m = __float_as_int(pt.w);

        float f1 = floorf(tm1), f2 = floorf(tm2);
        int if1 = (int)f1, if2 = (int)f2;
        int e1 = (if1 - 2) & ~1;                    // even base ROW
        int rpair = (e1 + j2) & 511;                // even → pair contiguous
        int csoff = (if2 & 511) - (band << 2);      // 0..3 (band-local col)

        // ---- weights (mirror of verified kernel: tm1↔tm2 swapped)
        float u1 = tm1 - (float)(e1 + j2);          // lane's row pair
        float wra = kbw(u1);
        float wrb = kbw(u1 - 1.0f);
        float fr2 = tm2 - f2;
        float wA = kbw(fr2 - fjm2);                 // col weights via DPP
        float wB = kbw(fr2 - fjp2);
        float w0_ = qdpp<0x00>(wA);
        float w1_ = qdpp<0x55>(wA);
        float w2_ = qdpp<0xAA>(wA);
        float w3_ = qdpp<0xFF>(wA);
        float w4_ = qdpp<0x00>(wB);
        float w5_ = qdpp<0x55>(wB);

        // ---- 6 col-slot reads from LDS (16B aligned: rpair even)
        const float* lp = lds + (rpair << 1) + csoff * 1028;
        f32x4 v0 = *(const f32x4*)(lp + 0 * 1028);
        f32x4 v1 = *(const f32x4*)(lp + 1 * 1028);
        f32x4 v2 = *(const f32x4*)(lp + 2 * 1028);
        f32x4 v3 = *(const f32x4*)(lp + 3 * 1028);
        f32x4 v4 = *(const f32x4*)(lp + 4 * 1028);
        f32x4 v5 = *(const f32x4*)(lp + 5 * 1028);

        // ---- fma chain (same shape as verified kernel; axes swapped)
        float c0re = w0_ * v0.x, c0im = w0_ * v0.y;   // row e1+2j
        float c1re = w0_ * v0.z, c1im = w0_ * v0.w;   // row e1+2j+1
        c0re = fmaf(w1_, v1.x, c0re); c0im = fmaf(w1_, v1.y, c0im);
        c1re = fmaf(w1_, v1.z, c1re); c1im = fmaf(w1_, v1.w, c1im);
        c0re = fmaf(w2_, v2.x, c0re); c0im = fmaf(w2_, v2.y, c0im);
        c1re = fmaf(w2_, v2.z, c1re); c1im = fmaf(w2_, v2.w, c1im);
        c0re = fmaf(w3_, v3.x, c0re); c0im = fmaf(w3_, v3.y, c0im);
        c1re = fmaf(w3_, v3.z, c1re); c1im = fmaf(w3_, v3.w, c1im);
        c0re = fmaf(w4_, v4.x, c0re); c0im = fmaf(w4_, v4.y, c0im);
        c1re = fmaf(w4_, v4.z, c1re); c1im = fmaf(w4_, v4.w, c1im);
        c0re = fmaf(w5_, v5.x, c0re); c0im = fmaf(w5_, v5.y, c0im);
        c1re = fmaf(w5_, v5.z, c1re); c1im = fmaf(w5_, v5.w, c1im);
        float p_re = fmaf(wra, c0re, wrb * c1re);
        float p_im = fmaf(wra, c0im, wrb * c1im);
        p_re += qdpp<0xB1>(p_re); p_re += qdpp<0x4E>(p_re);
        p_im += qdpp<0xB1>(p_im); p_im += qdpp<0x4E>(p_im);

        if (valid) {
            if (j == 0) out_re[m] = p_re * dd;
            else if (j == 1) out_im[m] = p_im * dd;
        }
    }
}

// ---------------------------------------------------------------- launch

extern "C" void kernel_launch(void* const* d_in, const int* in_sizes, int n_in,
                              void* d_out, int out_size, void* d_ws, size_t ws_size,
                              hipStream_t stream) {
    const float* image = (const float*)d_in[0];   // (8,256,256) f32
    const float* ktraj = (const float*)d_in[1];   // (8,2,131072) f32
    const float* dcf   = (const float*)d_in[2];   // (8,131072) f32
    float* out = (float*)d_out;                   // (2,8,131072) f32

    // workspace layout (bytes):
    //   T        @ 0          4,194,304   (4 pairs * 256*512 c64)
    //   kgridT   @ 4,194,304  16,777,216  (8 * 512*512 c64, TRANSPOSED)
    //   cursors  @ 20,971,520 4,096       (8 * 128 int)
    //   sortedpt @ 20,975,616 33,554,432  (8 * 128 bands * 2048 * float4)
    float2* T        = (float2*)d_ws;
    float2* kgridT   = T + (size_t)4 * 256 * GSZ;
    int*    cursors  = (int*)((char*)d_ws + 20971520);
    float4* sortedpt = (float4*)((char*)d_ws + 20975616);

    pass1_rowfft<<<512, 256, 0, stream>>>(image, T, cursors);
    pass2_colfft<<<512, 256, 0, stream>>>(T, kgridT, ktraj, dcf, cursors, sortedpt);
    interp_kb<<<1024, 256, 0, stream>>>(kgridT, cursors, sortedpt, out);
}

// Round 8
// 120.904 us; speedup vs baseline: 1.7908x; 1.0023x over previous
//
#include <hip/hip_runtime.h>
#include <math.h>

#define GSZ 512
#define NSZ 256
#define NBATCH 8
#define MPTS 131072
#define PI_F 3.14159265358979f
#define BETA_F 13.8551004f
#define BETA2_F (BETA_F * BETA_F)
#define RSQ2 0.70710678f
// LDS pad: +1 float2 every 8 → strided radix-8 access conflict-reduced
#define PADIDX(i) ((i) + ((i) >> 3))

typedef float f32x4 __attribute__((ext_vector_type(4)));

// ---------------------------------------------------------------- helpers

// Exact asymptotic de-apodization: st ∈ [13.03, 13.855] so
// st/sinh(st) = 2·st·e^(−st)·(1+O(e^(−2st))), rel err < 5e-12.
__device__ __forceinline__ float apod(int i) {
    float x = (float)(i - 128);
    float arg = PI_F * 6.0f * x * (1.0f / 512.0f);
    float t = BETA2_F - arg * arg;
    float st = sqrtf(t);
    return 2.0f * st * __expf(-st);
}

// Branchless Kaiser-Bessel weight, large-x asymptotic i0 (3 transcendentals).
__device__ __forceinline__ float kbw(float u) {
    float t = 1.0f - u * u * (1.0f / 9.0f);
    float x = BETA_F * sqrtf(fmaxf(t, 0.0f));
    float xc = fmaxf(x, 0.35f);
    float R = __builtin_amdgcn_rsqf(xc);
    float R2 = R * R;
    float q = R * (0.39894228f + R2 * (0.04986779f + R2 * 0.02804702f));
    float w = __expf(xc) * q;
    return (t > 0.0f) ? w : 0.0f;
}

// DPP quad_perm cross-lane (no DS pipe)
template<int CTRL>
__device__ __forceinline__ float qdpp(float v) {
    int r = __builtin_amdgcn_mov_dpp(__float_as_int(v), CTRL, 0xF, 0xF, true);
    return __int_as_float(r);
}

__device__ __forceinline__ float2 cadd(float2 a, float2 b){ return make_float2(a.x+b.x, a.y+b.y); }
__device__ __forceinline__ float2 csub(float2 a, float2 b){ return make_float2(a.x-b.x, a.y-b.y); }
__device__ __forceinline__ float2 cmul(float2 a, float2 b){ return make_float2(a.x*b.x-a.y*b.y, a.x*b.y+a.y*b.x); }
__device__ __forceinline__ float2 mul_negi(float2 a){ return make_float2(a.y, -a.x); }
__device__ __forceinline__ float2 mul_posi(float2 a){ return make_float2(-a.y, a.x); }
__device__ __forceinline__ float2 mul_w81(float2 a){ return make_float2(RSQ2*(a.x+a.y), RSQ2*(a.y-a.x)); }
__device__ __forceinline__ float2 mul_w83(float2 a){ return make_float2(RSQ2*(a.y-a.x), -RSQ2*(a.x+a.y)); }

__device__ __forceinline__ void dft8_combine(float2 E0, float2 E1, float2 E2, float2 E3,
                                             float2 O0, float2 O1, float2 O2, float2 O3,
                                             float2* y) {
    float2 c1 = mul_w81(O1), c2 = mul_negi(O2), c3 = mul_w83(O3);
    y[0] = cadd(E0, O0); y[4] = csub(E0, O0);
    y[1] = cadd(E1, c1); y[5] = csub(E1, c1);
    y[2] = cadd(E2, c2); y[6] = csub(E2, c2);
    y[3] = cadd(E3, c3); y[7] = csub(E3, c3);
}

__device__ __forceinline__ void dft8(const float2* x, float2* y) {
    float2 a0=x[0], a1=x[2], a2=x[4], a3=x[6];
    float2 b0=x[1], b1=x[3], b2=x[5], b3=x[7];
    float2 ta0=cadd(a0,a2), ta1=csub(a0,a2), ta2=cadd(a1,a3), ta3=csub(a1,a3);
    float2 E0=cadd(ta0,ta2), E2=csub(ta0,ta2);
    float2 E1=cadd(ta1, mul_negi(ta3)), E3=cadd(ta1, mul_posi(ta3));
    float2 tb0=cadd(b0,b2), tb1=csub(b0,b2), tb2=cadd(b1,b3), tb3=csub(b1,b3);
    float2 O0=cadd(tb0,tb2), O2=csub(tb0,tb2);
    float2 O1=cadd(tb1, mul_negi(tb3)), O3=cadd(tb1, mul_posi(tb3));
    dft8_combine(E0,E1,E2,E3,O0,O1,O2,O3,y);
}

__device__ __forceinline__ void dft8_pruned(float2 x0, float2 x1, float2 x6, float2 x7, float2* y) {
    float2 E0 = cadd(x0, x6), E2 = csub(x0, x6);
    float2 E1 = cadd(x0, mul_posi(x6)), E3 = cadd(x0, mul_negi(x6));
    float2 O0 = cadd(x1, x7), O2 = csub(x1, x7);
    float2 O1 = cadd(x1, mul_posi(x7)), O3 = cadd(x1, mul_negi(x7));
    dft8_combine(E0,E1,E2,E3,O0,O1,O2,O3,y);
}

template<int S>
__device__ __forceinline__ void twiddle8(int t, float2* y) {
    if (S < 2) {
        int j = (S == 0) ? t : (t >> 3);
        const float scale = (S == 0) ? (-2.0f*PI_F/512.0f) : (-2.0f*PI_F/64.0f);
        float theta = scale * (float)j;
        float sn, cs;
        __sincosf(theta, &sn, &cs);              // sin FIRST, cos second
        float2 w = make_float2(cs, sn), wq = w;
        y[1] = cmul(y[1], wq);
        #pragma unroll
        for (int q = 2; q < 8; ++q) { wq = cmul(wq, w); y[q] = cmul(y[q], wq); }
    }
}

// ----- pair-cooperative half-butterfly primitives (pass 1, 128 thr/row) ---

__device__ __forceinline__ float2 pswap(float2 v) {
    return make_float2(qdpp<0xB1>(v.x), qdpp<0xB1>(v.y));
}

__device__ __forceinline__ void dft8_half(const float2* v, float2* EO) {
    float2 t0 = cadd(v[0], v[2]), t1 = csub(v[0], v[2]);
    float2 t2 = cadd(v[1], v[3]), t3 = csub(v[1], v[3]);
    EO[0] = cadd(t0, t2); EO[2] = csub(t0, t2);
    EO[1] = cadd(t1, mul_negi(t3)); EO[3] = cadd(t1, mul_posi(t3));
}

__device__ __forceinline__ void dft8p_half(float2 u0, float2 u1, float2* EO) {
    EO[0] = cadd(u0, u1); EO[2] = csub(u0, u1);
    EO[1] = cadd(u0, mul_posi(u1)); EO[3] = cadd(u0, mul_negi(u1));
}

__device__ __forceinline__ void combine_half(int h, const float2* V, float2* y) {
    float2 P0 = pswap(V[0]), P1 = pswap(V[1]), P2 = pswap(V[2]), P3 = pswap(V[3]);
    float2 E0 = h ? P0 : V[0], O0 = h ? V[0] : P0;
    float2 E1 = h ? P1 : V[1], O1 = h ? V[1] : P1;
    float2 E2 = h ? P2 : V[2], O2 = h ? V[2] : P2;
    float2 E3 = h ? P3 : V[3], O3 = h ? V[3] : P3;
    float2 c1 = mul_w81(O1), c2 = mul_negi(O2), c3 = mul_w83(O3);
    float s = h ? -1.0f : 1.0f;
    y[0] = make_float2(fmaf(s, O0.x, E0.x), fmaf(s, O0.y, E0.y));
    y[1] = make_float2(fmaf(s, c1.x, E1.x), fmaf(s, c1.y, E1.y));
    y[2] = make_float2(fmaf(s, c2.x, E2.x), fmaf(s, c2.y, E2.y));
    y[3] = make_float2(fmaf(s, c3.x, E3.x), fmaf(s, c3.y, E3.y));
}

__device__ __forceinline__ void twiddle4h(int jidx, float scale, int h, float2* y) {
    float theta = scale * (float)jidx;
    float sn, cs;
    __sincosf(theta, &sn, &cs);                  // sin FIRST, cos second
    float2 w = make_float2(cs, sn);
    float2 w2 = cmul(w, w);
    float2 w4 = cmul(w2, w2);
    float2 m = h ? w4 : make_float2(1.0f, 0.0f);
    y[0] = cmul(y[0], m);
    float2 wq = cmul(m, w); y[1] = cmul(y[1], wq);
    wq = cmul(wq, w);       y[2] = cmul(y[2], wq);
    wq = cmul(wq, w);       y[3] = cmul(y[3], wq);
}

// ---------------------------------------------------------------- pass 1
// Grid-fused: blocks [0,512) = pair-cooperative row FFT (r4, verified);
// blocks [512,1024) = LDS-aggregated counting-sort scatter (r6 logic,
// halved to 2048 pts/block so LDS = 34 KB → 4 blocks/CU for the whole
// kernel). Scatter has no dependency on the FFT — it overlaps freely.
// cursors are zeroed by hipMemsetAsync before this kernel.
__global__ __launch_bounds__(256) void pass1_rowfft(const float* __restrict__ image,
                                                    float2* __restrict__ T,
                                                    const float* __restrict__ ktraj,
                                                    const float* __restrict__ dcf,
                                                    int* __restrict__ cursors,
                                                    float4* __restrict__ sortedpt) {
    __shared__ float4 smemBuf[2176];                // 34,816 B (union)
    int tid = threadIdx.x;
    int blk = blockIdx.x;

    if (blk >= 512) {
        // ---------------- scatter: 2048 pts/block, key = tm2 col-band
        int u = blk - 512;
        int bs = u >> 6, seg = u & 63;              // 8 batches × 64 segs × 2048
        const float SCALE = (float)GSZ / (2.0f * PI_F);
        const float* kt1 = ktraj + (size_t)(bs * 2) * MPTS;
        const float* kt2 = kt1 + MPTS;
        const float* dcfb = dcf + ((size_t)bs << 17);
        int* cur = cursors + (bs << 7);
        float4* sp = sortedpt + ((size_t)bs << 18); // 128 bands * 2048 slots

        float4* pts = smemBuf;                      // [2048]
        int* hist = (int*)(smemBuf + 2048);         // [128]
        int* lofs = hist + 128;                     // [128]
        int* gbase = hist + 256;                    // [128]
        int* lcur = hist + 384;                     // [128]

        if (tid < 128) hist[tid] = 0;
        __syncthreads();

        // phase 1: load 8 pts/thread, LDS histogram
        float t1v[8], t2v[8], dv[8];
        #pragma unroll
        for (int k = 0; k < 8; ++k) {
            int m = (seg << 11) + (k << 8) + tid;
            t1v[k] = kt1[m] * SCALE;
            t2v[k] = kt2[m] * SCALE;
            dv[k]  = dcfb[m];
            int key = (((int)floorf(t2v[k])) & 511) >> 2;
            atomicAdd(&hist[key], 1);
        }
        __syncthreads();

        // phase 2: serial prefix (128 adds) + 128 global atomics
        if (tid == 0) {
            int s = 0;
            #pragma unroll 8
            for (int i = 0; i < 128; ++i) { lofs[i] = s; s += hist[i]; }
        }
        if (tid < 128) { gbase[tid] = atomicAdd(cur + tid, hist[tid]); lcur[tid] = 0; }
        __syncthreads();

        // phase 3: reorder into LDS by band (band packed into index word)
        #pragma unroll
        for (int k = 0; k < 8; ++k) {
            int m = (seg << 11) + (k << 8) + tid;
            int key = (((int)floorf(t2v[k])) & 511) >> 2;
            int loc = atomicAdd(&lcur[key], 1);
            pts[lofs[key] + loc] =
                make_float4(t1v[k], t2v[k], dv[k], __int_as_float((key << 17) | m));
        }
        __syncthreads();

        // phase 4: slot-ordered copy-out — coalesced ~256B bursts per band
        #pragma unroll
        for (int k = 0; k < 8; ++k) {
            int s = (k << 8) + tid;
            float4 p = pts[s];
            int w = __float_as_int(p.w);
            int key = w >> 17;
            int m = w & 0x1FFFF;
            int gpos = gbase[key] + (s - lofs[key]);
            if (gpos < 2048)
                sp[((size_t)key << 11) + gpos] =
                    make_float4(p.x, p.y, p.z, __int_as_float(m));
        }
        return;
    }

    // ---------------- row FFT (verified r4 math, unchanged)
    float2 (*sm)[2][578] = reinterpret_cast<float2(*)[2][578]>(smemBuf);
    int r = tid >> 7;                               // row within block {0,1}
    int tt = tid & 127;
    int h = tt & 1;                                 // butterfly half (E/O)
    int b = tt >> 1;                                // butterfly index 0..63
    int p = blk & 3;                                // batch pair 0..3
    int g = blk >> 2;                               // 0..127
    int rp = (g << 1) + r;                          // compact row 0..255
    int y = (rp < 128) ? rp : (rp + 256);
    int iy = (y < 128) ? (y + 128) : (y - 384);
    float ay = apod(iy);
    const float* irow0 = image + ((size_t)((2 * p)     * NSZ + iy)) * NSZ;
    const float* irow1 = image + ((size_t)((2 * p + 1) * NSZ + iy)) * NSZ;

    float2 y4[4];
    {
        int iA = h ? (b + 192) : (b + 128);
        int iB = h ? (b + 64)  : b;
        float wA = ay * apod(iA), wB = ay * apod(iB);
        float2 u0 = make_float2(irow0[iA] * wA, irow1[iA] * wA);
        float2 u1 = make_float2(irow0[iB] * wB, irow1[iB] * wB);
        float2 EO[4];
        dft8p_half(u0, u1, EO);
        combine_half(h, EO, y4);
        twiddle4h(b, -2.0f * PI_F / 512.0f, h, y4);
    }
    float2* A  = sm[0][r];
    float2* Bf = sm[1][r];
    #pragma unroll
    for (int qq = 0; qq < 4; ++qq) A[PADIDX((b << 3) + (h << 2) + qq)] = y4[qq];
    __syncthreads();
    {
        float2 v[4];
        #pragma unroll
        for (int i = 0; i < 4; ++i) v[i] = A[PADIDX(b + (((i << 1) + h) << 6))];
        float2 EO[4];
        dft8_half(v, EO);
        combine_half(h, EO, y4);
        twiddle4h(b >> 3, -2.0f * PI_F / 64.0f, h, y4);
        int base = (b & 7) + ((b >> 3) << 6);
        #pragma unroll
        for (int qq = 0; qq < 4; ++qq) Bf[PADIDX(base + (((h << 2) + qq) << 3))] = y4[qq];
    }
    __syncthreads();
    {
        float2 v[4];
        #pragma unroll
        for (int i = 0; i < 4; ++i) v[i] = Bf[PADIDX(b + (((i << 1) + h) << 6))];
        float2 EO[4];
        dft8_half(v, EO);
        combine_half(h, EO, y4);
        float2* Trow = T + (((size_t)(p << 8) + rp) << 9);
        #pragma unroll
        for (int qq = 0; qq < 4; ++qq) Trow[b + (((h << 2) + qq) << 6)] = y4[qq];
    }
}

// ---------------------------------------------------------------- pass 2
// FFT-only again (37 KB LDS → 4 blocks/CU restored). Column FFT +
// Hermitian unpack, TRANSPOSED store kgridT[col][row] (r7, verified).
__global__ __launch_bounds__(256) void pass2_colfft(const float2* __restrict__ T,
                                                    float2* __restrict__ kgridT) {
    __shared__ float2 B[8][578];                    // 36,992 B → 4 blocks/CU
    int tid = threadIdx.x;
    int blk = blockIdx.x;
    int p = blk & 3;                                // batch pair
    int g = blk >> 2;                               // 0..63 col group
    const float2* Tb = T + ((size_t)p << 17);       // 256*512 per pair
    float2* Kb0 = kgridT + ((size_t)(2 * p) << 18);
    float2* Kb1 = Kb0 + ((size_t)1 << 18);

    #define COLG(c) ((g > 0) ? (((c) < 4) ? ((g << 2) + (c)) : (505 - (g << 2) + (c))) \
                             : (((c) < 4) ? (c) : (((c) == 7) ? 256 : (505 + (c)))))

    {
        int c = tid & 7, r0 = tid >> 3;             // r0 0..31
        int colg = COLG(c);
        #pragma unroll
        for (int k = 0; k < 8; ++k) {
            int rr = r0 + (k << 5);
            B[c][PADIDX(rr)] = Tb[((size_t)rr << 9) + colg];
        }
    }
    __syncthreads();
    int t = tid & 63;
    int c0 = tid >> 6;                              // slots c0 and c0+4
    float2* Ba = B[c0];
    float2* Bb = B[c0 + 4];
    float2 ya[8], yb[8];
    {
        float2 a0 = Ba[PADIDX(t)],       a1 = Ba[PADIDX(t + 64)];
        float2 a6 = Ba[PADIDX(t + 128)], a7 = Ba[PADIDX(t + 192)];
        float2 b0 = Bb[PADIDX(t)],       b1 = Bb[PADIDX(t + 64)];
        float2 b6 = Bb[PADIDX(t + 128)], b7 = Bb[PADIDX(t + 192)];
        dft8_pruned(a0, a1, a6, a7, ya); twiddle8<0>(t, ya);
        dft8_pruned(b0, b1, b6, b7, yb); twiddle8<0>(t, yb);
    }
    __syncthreads();
    #pragma unroll
    for (int q = 0; q < 8; ++q) {
        Ba[PADIDX((t << 3) + q)] = ya[q];
        Bb[PADIDX((t << 3) + q)] = yb[q];
    }
    __syncthreads();
    {
        float2 xa[8], xb[8];
        #pragma unroll
        for (int pp = 0; pp < 8; ++pp) { xa[pp] = Ba[PADIDX(t + (pp << 6))]; xb[pp] = Bb[PADIDX(t + (pp << 6))]; }
        dft8(xa, ya); twiddle8<1>(t, ya);
        dft8(xb, yb); twiddle8<1>(t, yb);
    }
    __syncthreads();
    {
        int j = t >> 3, k = t & 7, base = k + (j << 6);
        #pragma unroll
        for (int q = 0; q < 8; ++q) {
            Ba[PADIDX(base + (q << 3))] = ya[q];
            Bb[PADIDX(base + (q << 3))] = yb[q];
        }
    }
    __syncthreads();
    {
        float2 xa[8], xb[8];
        #pragma unroll
        for (int pp = 0; pp < 8; ++pp) { xa[pp] = Ba[PADIDX(t + (pp << 6))]; xb[pp] = Bb[PADIDX(t + (pp << 6))]; }
        dft8(xa, ya);
        dft8(xb, yb);
    }
    __syncthreads();
    #pragma unroll
    for (int q = 0; q < 8; ++q) {
        Ba[PADIDX(t + (q << 6))] = ya[q];
        Bb[PADIDX(t + (q << 6))] = yb[q];
    }
    __syncthreads();
    {
        int c = tid & 7, r0 = tid >> 3;
        int colg = COLG(c);
        int mc = 7 - c;
        if (g == 0) { if (c == 0) mc = 0; else if (c == 7) mc = 7; }
        #pragma unroll
        for (int k = 0; k < 16; ++k) {
            int rr = r0 + (k << 5);
            int mr = (512 - rr) & 511;
            float2 Z = B[c][PADIDX(rr)];
            float2 M = B[mc][PADIDX(mr)];
            float2 K0 = make_float2(0.5f * (Z.x + M.x), 0.5f * (Z.y - M.y));
            float2 K1 = make_float2(0.5f * (Z.y + M.y), 0.5f * (M.x - Z.x));
            size_t off = ((size_t)colg << 9) + rr;   // TRANSPOSED: [col][row]
            Kb0[off] = K0;
            Kb1[off] = K1;
        }
    }
    #undef COLG
}

// ---------------------------------------------------------------- pass 3
// Band-local KB gather on the TRANSPOSED grid (r7, verified).
__global__ __launch_bounds__(256) void interp_kb(const float2* __restrict__ kgridT,
                                                 const int* __restrict__ cursors,
                                                 const float4* __restrict__ sortedpt,
                                                 float* __restrict__ out) {
    __shared__ float lds[9 * 1028];                 // 37,008 B → 4 blocks/CU
    int tid = threadIdx.x;
    int blk = blockIdx.x;
    int b = blk & 7;                                // XCD affinity on batch
    int band = blk >> 3;                            // 0..127 (col bands)
    int j = tid & 3;                                // lane within quad
    int q = tid >> 2;                               // quad 0..63
    int j2 = j << 1;
    float fjm2 = (float)(j - 2), fjp2 = (float)(j + 2);

    int cnt = cursors[(b << 7) + band];
    cnt = (cnt > 2048) ? 2048 : cnt;
    if (cnt == 0) return;                           // block-uniform, pre-sync

    // ---- stage 9 kgridT rows (grid cols band*4-2 .. +6, mod 512)
    const float2* Kb = kgridT + ((size_t)b << 18);
    #pragma unroll
    for (int r = 0; r < 9; ++r) {
        int gc = ((band << 2) - 2 + r) & 511;
        const float4* src = (const float4*)(Kb + ((size_t)gc << 9));
        *(float4*)(lds + r * 1028 + (tid << 2)) = src[tid];
    }
    __syncthreads();

    const float4* sp = sortedpt + ((size_t)b << 18) + ((size_t)band << 11);
    float* out_re = out + ((size_t)b << 17);
    float* out_im = out_re + (size_t)NBATCH * MPTS;

    int iters = (cnt + 63) >> 6;
    for (int it = 0; it < iters; ++it) {
        int pidx = (it << 6) + q;
        bool valid = pidx < cnt;
        float4 pt = sp[valid ? pidx : 0];           // quad-uniform address
        float tm1 = pt.x, tm2 = pt.y, dd = pt.z;
        int m = __float_as_int(pt.w);

        float f1 = floorf(tm1), f2 = floorf(tm2);
        int if1 = (int)f1, if2 = (int)f2;
        int e1 = (if1 - 2) & ~1;                    // even base ROW
        int rpair = (e1 + j2) & 511;                // even → pair contiguous
        int csoff = (if2 & 511) - (band << 2);      // 0..3 (band-local col)

        // ---- weights (mirror of verified kernel: tm1↔tm2 swapped)
        float u1 = tm1 - (float)(e1 + j2);          // lane's row pair
        float wra = kbw(u1);
        float wrb = kbw(u1 - 1.0f);
        float fr2 = tm2 - f2;
        float wA = kbw(fr2 - fjm2);                 // col weights via DPP
        float wB = kbw(fr2 - fjp2);
        float w0_ = qdpp<0x00>(wA);
        float w1_ = qdpp<0x55>(wA);
        float w2_ = qdpp<0xAA>(wA);
        float w3_ = qdpp<0xFF>(wA);
        float w4_ = qdpp<0x00>(wB);
        float w5_ = qdpp<0x55>(wB);

        // ---- 6 col-slot reads from LDS (16B aligned: rpair even)
        const float* lp = lds + (rpair << 1) + csoff * 1028;
        f32x4 v0 = *(const f32x4*)(lp + 0 * 1028);
        f32x4 v1 = *(const f32x4*)(lp + 1 * 1028);
        f32x4 v2 = *(const f32x4*)(lp + 2 * 1028);
        f32x4 v3 = *(const f32x4*)(lp + 3 * 1028);
        f32x4 v4 = *(const f32x4*)(lp + 4 * 1028);
        f32x4 v5 = *(const f32x4*)(lp + 5 * 1028);

        // ---- fma chain (same shape as verified kernel; axes swapped)
        float c0re = w0_ * v0.x, c0im = w0_ * v0.y;   // row e1+2j
        float c1re = w0_ * v0.z, c1im = w0_ * v0.w;   // row e1+2j+1
        c0re = fmaf(w1_, v1.x, c0re); c0im = fmaf(w1_, v1.y, c0im);
        c1re = fmaf(w1_, v1.z, c1re); c1im = fmaf(w1_, v1.w, c1im);
        c0re = fmaf(w2_, v2.x, c0re); c0im = fmaf(w2_, v2.y, c0im);
        c1re = fmaf(w2_, v2.z, c1re); c1im = fmaf(w2_, v2.w, c1im);
        c0re = fmaf(w3_, v3.x, c0re); c0im = fmaf(w3_, v3.y, c0im);
        c1re = fmaf(w3_, v3.z, c1re); c1im = fmaf(w3_, v3.w, c1im);
        c0re = fmaf(w4_, v4.x, c0re); c0im = fmaf(w4_, v4.y, c0im);
        c1re = fmaf(w4_, v4.z, c1re); c1im = fmaf(w4_, v4.w, c1im);
        c0re = fmaf(w5_, v5.x, c0re); c0im = fmaf(w5_, v5.y, c0im);
        c1re = fmaf(w5_, v5.z, c1re); c1im = fmaf(w5_, v5.w, c1im);
        float p_re = fmaf(wra, c0re, wrb * c1re);
        float p_im = fmaf(wra, c0im, wrb * c1im);
        p_re += qdpp<0xB1>(p_re); p_re += qdpp<0x4E>(p_re);
        p_im += qdpp<0xB1>(p_im); p_im += qdpp<0x4E>(p_im);

        if (valid) {
            if (j == 0) out_re[m] = p_re * dd;
            else if (j == 1) out_im[m] = p_im * dd;
        }
    }
}

// ---------------------------------------------------------------- launch

extern "C" void kernel_launch(void* const* d_in, const int* in_sizes, int n_in,
                              void* d_out, int out_size, void* d_ws, size_t ws_size,
                              hipStream_t stream) {
    const float* image = (const float*)d_in[0];   // (8,256,256) f32
    const float* ktraj = (const float*)d_in[1];   // (8,2,131072) f32
    const float* dcf   = (const float*)d_in[2];   // (8,131072) f32
    float* out = (float*)d_out;                   // (2,8,131072) f32

    // workspace layout (bytes):
    //   T        @ 0          4,194,304   (4 pairs * 256*512 c64)
    //   kgridT   @ 4,194,304  16,777,216  (8 * 512*512 c64, TRANSPOSED)
    //   cursors  @ 20,971,520 4,096       (8 * 128 int)
    //   sortedpt @ 20,975,616 33,554,432  (8 * 128 bands * 2048 * float4)
    float2* T        = (float2*)d_ws;
    float2* kgridT   = T + (size_t)4 * 256 * GSZ;
    int*    cursors  = (int*)((char*)d_ws + 20971520);
    float4* sortedpt = (float4*)((char*)d_ws + 20975616);

    hipMemsetAsync(cursors, 0, 1024 * sizeof(int), stream);   // stream-ordered, capture-safe
    pass1_rowfft<<<1024, 256, 0, stream>>>(image, T, ktraj, dcf, cursors, sortedpt);
    pass2_colfft<<<256, 256, 0, stream>>>(T, kgridT);
    interp_kb<<<1024, 256, 0, stream>>>(kgridT, cursors, sortedpt, out);
}